// Round 1
// baseline (2149.313 us; speedup 1.0000x reference)
//
#include <hip/hip_runtime.h>
#include <hip/hip_bf16.h>

#define B_  4
#define T_  2048
#define D_  1024
#define H_  16
#define HD_ 64
#define M_  (B_ * T_)          // 8192 rows of x
#define NQKV_ (3 * H_ * HD_)   // 3072 output cols of fused qkv gemm

// ---------------------------------------------------------------------------
// Kernel 1: fused QKV projection.  C[m][n], n in [0,3072):
//   sel = n>>10 (0=q,1=k,2=v), h = (n>>6)&15, e = n&63.
//   Each 64-wide n-tile lies entirely inside one (sel, h) block.
// Output layout: q/k/v[(b*H+h)*T + t][e]  (per-head rows, coalesced for attn)
// ---------------------------------------------------------------------------
__global__ __launch_bounds__(256) void qkv_gemm(
        const float* __restrict__ x,
        const float* __restrict__ Wq, const float* __restrict__ Wk,
        const float* __restrict__ Wv,
        float* __restrict__ qws, float* __restrict__ kws, float* __restrict__ vws) {
    const int BM = 64, BN = 64, BK = 16;
    __shared__ float As[BK][BM];
    __shared__ float Bs[BK][BN];

    const int n0 = blockIdx.x * BN;
    const int m0 = blockIdx.y * BM;
    const int tid = threadIdx.x;
    const int sel = n0 >> 10;
    const int h = (n0 >> 6) & (H_ - 1);
    const float* W = (sel == 0 ? Wq : (sel == 1 ? Wk : Wv)) + (size_t)h * D_ * HD_;

    const int tx = tid & 15, ty = tid >> 4;
    float acc[4][4] = {};

    for (int k0 = 0; k0 < D_; k0 += BK) {
        // A tile: 64 rows x 16 k, one float4 per thread
        {
            int mm = tid >> 2, kk4 = (tid & 3) * 4;
            float4 a = *(const float4*)&x[(size_t)(m0 + mm) * D_ + k0 + kk4];
            As[kk4 + 0][mm] = a.x; As[kk4 + 1][mm] = a.y;
            As[kk4 + 2][mm] = a.z; As[kk4 + 3][mm] = a.w;
        }
        // B tile: 16 k x 64 n (= e within head), one float4 per thread
        {
            int kk = tid >> 4, nn4 = (tid & 15) * 4;
            *(float4*)&Bs[kk][nn4] = *(const float4*)&W[(size_t)(k0 + kk) * HD_ + nn4];
        }
        __syncthreads();
        #pragma unroll
        for (int kx = 0; kx < BK; ++kx) {
            float4 av = *(const float4*)&As[kx][ty * 4];
            float4 bv = *(const float4*)&Bs[kx][tx * 4];
            float a4[4] = {av.x, av.y, av.z, av.w};
            float b4[4] = {bv.x, bv.y, bv.z, bv.w};
            #pragma unroll
            for (int i = 0; i < 4; ++i)
                #pragma unroll
                for (int j = 0; j < 4; ++j)
                    acc[i][j] += a4[i] * b4[j];
        }
        __syncthreads();
    }

    float* outp = (sel == 0 ? qws : (sel == 1 ? kws : vws));
    #pragma unroll
    for (int i = 0; i < 4; ++i) {
        int m = m0 + ty * 4 + i;
        int b = m / T_, t = m % T_;        // pow2 -> shifts
        float* row = outp + ((size_t)(b * H_ + h) * T_ + t) * HD_ + tx * 4;
        #pragma unroll
        for (int j = 0; j < 4; ++j) row[j] = acc[i][j];
    }
}

// ---------------------------------------------------------------------------
// Kernel 2: causal flash attention, fp32.
// grid = (T/256, B*H); block = 256 threads; one query row per thread.
// K/V staged in 64-row LDS tiles; all lanes read the same LDS address in the
// inner loops (hardware broadcast, conflict-free). Online softmax in chunks
// of 8 so s[]/p[] stay statically indexed (registers, not scratch).
// Output layout: O[(b*T + t)][h*64 + e]  (ready for the output projection)
// ---------------------------------------------------------------------------
__global__ __launch_bounds__(256) void attn_fwd(
        const float* __restrict__ qws, const float* __restrict__ kws,
        const float* __restrict__ vws, float* __restrict__ Ows) {
    __shared__ float Ks[64][HD_];
    __shared__ float Vs[64][HD_];

    const int bh = blockIdx.y;         // b*H + h
    const int b = bh >> 4, h = bh & (H_ - 1);
    const int tid = threadIdx.x;
    const int t = blockIdx.x * 256 + tid;

    float q[HD_];
    {
        const float* qrow = qws + ((size_t)bh * T_ + t) * HD_;
        #pragma unroll
        for (int e = 0; e < HD_; ++e) q[e] = qrow[e] * 0.125f;  // 1/sqrt(64)
    }
    float o[HD_] = {};
    float m = -INFINITY, l = 0.f;

    const int jend = blockIdx.x * 256 + 255;   // max t in this block
    for (int jt = 0; jt <= jend; jt += 64) {
        // stage K,V tile (64 x 64), 4 float4 per thread each
        #pragma unroll
        for (int i = 0; i < 4; ++i) {
            int idx = i * 256 + tid;
            int r = idx >> 4, c = (idx & 15) * 4;
            *(float4*)&Ks[r][c] = *(const float4*)&kws[((size_t)bh * T_ + jt + r) * HD_ + c];
            *(float4*)&Vs[r][c] = *(const float4*)&vws[((size_t)bh * T_ + jt + r) * HD_ + c];
        }
        __syncthreads();

        if (jt <= t) {
            #pragma unroll 1
            for (int c0 = 0; c0 < 64; c0 += 8) {
                if (jt + c0 > t) break;          // whole chunk masked
                float s[8];
                #pragma unroll
                for (int ci = 0; ci < 8; ++ci) {
                    const float* kr = &Ks[c0 + ci][0];
                    float acc = 0.f;
                    #pragma unroll
                    for (int e = 0; e < HD_; ++e) acc += q[e] * kr[e];
                    s[ci] = (jt + c0 + ci <= t) ? acc : -INFINITY;
                }
                float cmax = s[0];
                #pragma unroll
                for (int ci = 1; ci < 8; ++ci) cmax = fmaxf(cmax, s[ci]);
                float mn = fmaxf(m, cmax);       // finite: s[0] is unmasked
                float corr = __expf(m - mn);     // m=-inf first time -> 0
                float p[8]; float psum = 0.f;
                #pragma unroll
                for (int ci = 0; ci < 8; ++ci) { p[ci] = __expf(s[ci] - mn); psum += p[ci]; }
                l = l * corr + psum;
                #pragma unroll
                for (int e = 0; e < HD_; ++e) o[e] *= corr;
                #pragma unroll
                for (int ci = 0; ci < 8; ++ci) {
                    float pv = p[ci];
                    const float* vr = &Vs[c0 + ci][0];
                    #pragma unroll
                    for (int e = 0; e < HD_; ++e) o[e] += pv * vr[e];
                }
                m = mn;
            }
        }
        __syncthreads();
    }

    const float inv = 1.f / l;
    float* orow = Ows + ((size_t)(b * T_ + t)) * (H_ * HD_) + h * HD_;
    #pragma unroll
    for (int e = 0; e < HD_; ++e) orow[e] = o[e] * inv;
}

// ---------------------------------------------------------------------------
// Kernel 3: output projection  out = O @ Wp + bp.  (8192 x 1024 x 1024)
// ---------------------------------------------------------------------------
__global__ __launch_bounds__(256) void proj_gemm(
        const float* __restrict__ A, const float* __restrict__ Wp,
        const float* __restrict__ bp, float* __restrict__ out) {
    const int BM = 64, BN = 64, BK = 16;
    __shared__ float As[BK][BM];
    __shared__ float Bs[BK][BN];

    const int n0 = blockIdx.x * BN;
    const int m0 = blockIdx.y * BM;
    const int tid = threadIdx.x;
    const int tx = tid & 15, ty = tid >> 4;
    float acc[4][4] = {};

    for (int k0 = 0; k0 < D_; k0 += BK) {    // K = H*HD = 1024
        {
            int mm = tid >> 2, kk4 = (tid & 3) * 4;
            float4 a = *(const float4*)&A[(size_t)(m0 + mm) * D_ + k0 + kk4];
            As[kk4 + 0][mm] = a.x; As[kk4 + 1][mm] = a.y;
            As[kk4 + 2][mm] = a.z; As[kk4 + 3][mm] = a.w;
        }
        {
            int kk = tid >> 4, nn4 = (tid & 15) * 4;
            *(float4*)&Bs[kk][nn4] = *(const float4*)&Wp[(size_t)(k0 + kk) * D_ + n0 + nn4];
        }
        __syncthreads();
        #pragma unroll
        for (int kx = 0; kx < BK; ++kx) {
            float4 av = *(const float4*)&As[kx][ty * 4];
            float4 bv = *(const float4*)&Bs[kx][tx * 4];
            float a4[4] = {av.x, av.y, av.z, av.w};
            float b4[4] = {bv.x, bv.y, bv.z, bv.w};
            #pragma unroll
            for (int i = 0; i < 4; ++i)
                #pragma unroll
                for (int j = 0; j < 4; ++j)
                    acc[i][j] += a4[i] * b4[j];
        }
        __syncthreads();
    }

    #pragma unroll
    for (int i = 0; i < 4; ++i) {
        int mrow = m0 + ty * 4 + i;
        #pragma unroll
        for (int j = 0; j < 4; ++j) {
            int n = n0 + tx * 4 + j;
            out[(size_t)mrow * D_ + n] = acc[i][j] + bp[n];
        }
    }
}

// ---------------------------------------------------------------------------
extern "C" void kernel_launch(void* const* d_in, const int* in_sizes, int n_in,
                              void* d_out, int out_size, void* d_ws, size_t ws_size,
                              hipStream_t stream) {
    const float* x  = (const float*)d_in[0];
    const float* Wq = (const float*)d_in[1];
    const float* Wk = (const float*)d_in[2];
    const float* Wv = (const float*)d_in[3];
    const float* Wp = (const float*)d_in[4];
    const float* bp = (const float*)d_in[5];
    float* out = (float*)d_out;

    const size_t per = (size_t)B_ * H_ * T_ * HD_;   // 8,388,608 floats
    float* qws = (float*)d_ws;
    float* kws = qws + per;
    float* vws = kws + per;
    float* Ows = vws + per;                           // [B*T][H*HD]

    // 1) QKV projection
    {
        dim3 grid(NQKV_ / 64, M_ / 64);
        qkv_gemm<<<grid, 256, 0, stream>>>(x, Wq, Wk, Wv, qws, kws, vws);
    }
    // 2) causal attention
    {
        dim3 grid(T_ / 256, B_ * H_);
        attn_fwd<<<grid, 256, 0, stream>>>(qws, kws, vws, Ows);
    }
    // 3) output projection + bias
    {
        dim3 grid(D_ / 64, M_ / 64);
        proj_gemm<<<grid, 256, 0, stream>>>(Ows, Wp, bp, out);
    }
}

// Round 2
// 598.461 us; speedup vs baseline: 3.5914x; 3.5914x over previous
//
#include <hip/hip_runtime.h>
#include <hip/hip_bf16.h>

#define B_  4
#define T_  2048
#define D_  1024
#define H_  16
#define HD_ 64
#define M_  (B_ * T_)          // 8192 rows
#define BH_ (B_ * H_)          // 64

typedef __attribute__((ext_vector_type(8))) short   short8;   // 8 x bf16 (4 VGPR)
typedef __attribute__((ext_vector_type(4))) float   f32x4;
typedef __attribute__((ext_vector_type(4))) unsigned short us4v;

#define MFMA16(a, b, c) __builtin_amdgcn_mfma_f32_16x16x32_bf16((a), (b), (c), 0, 0, 0)

__device__ __forceinline__ unsigned short f2bf(float f) {
    union { float f; unsigned u; } v; v.f = f;
    unsigned r = v.u + 0x7fffu + ((v.u >> 16) & 1u);   // round-nearest-even
    return (unsigned short)(r >> 16);
}

__device__ __forceinline__ void gl_lds16(const void* g, void* l) {
    __builtin_amdgcn_global_load_lds(
        (const __attribute__((address_space(1))) void*)g,
        (__attribute__((address_space(3))) void*)l, 16, 0, 0);
}

// ---------------------------------------------------------------------------
// Convert x (fp32) -> bf16, same layout.
// ---------------------------------------------------------------------------
__global__ __launch_bounds__(256) void cvt_x(const float* __restrict__ x,
                                             unsigned short* __restrict__ xb, int n4) {
    int i = blockIdx.x * 256 + threadIdx.x;
    if (i < n4) {
        float4 v = ((const float4*)x)[i];
        us4v o;
        o[0] = f2bf(v.x); o[1] = f2bf(v.y); o[2] = f2bf(v.z); o[3] = f2bf(v.w);
        ((us4v*)xb)[i] = o;
    }
}

// ---------------------------------------------------------------------------
// Transpose+convert: src fp32 row-major, 64x64 tiles -> dst[n][k] bf16.
//   dst row = dst_row_base + z*64 + (c0 + c);  dst col = r0 + r;  dst ld = dst_ld
// ---------------------------------------------------------------------------
__global__ __launch_bounds__(256) void tcvt(const float* __restrict__ src,
                                            unsigned short* __restrict__ dst,
                                            int src_ld, long src_z_str,
                                            int dst_row_base, int dst_ld) {
    __shared__ float tile[64][65];
    const float* s = src + (size_t)blockIdx.z * src_z_str;
    int r0 = blockIdx.x * 64, c0 = blockIdx.y * 64;
    int tid = threadIdx.x;
    #pragma unroll
    for (int i = 0; i < 4; ++i) {
        int idx4 = i * 256 + tid;            // 0..1023 float4s
        int r = idx4 >> 4, c4 = (idx4 & 15) * 4;
        float4 v = *(const float4*)&s[(size_t)(r0 + r) * src_ld + c0 + c4];
        tile[r][c4 + 0] = v.x; tile[r][c4 + 1] = v.y;
        tile[r][c4 + 2] = v.z; tile[r][c4 + 3] = v.w;
    }
    __syncthreads();
    #pragma unroll
    for (int i = 0; i < 4; ++i) {
        int idx4 = i * 256 + tid;
        int c = idx4 >> 4, r4 = (idx4 & 15) * 4;
        us4v o;
        o[0] = f2bf(tile[r4 + 0][c]); o[1] = f2bf(tile[r4 + 1][c]);
        o[2] = f2bf(tile[r4 + 2][c]); o[3] = f2bf(tile[r4 + 3][c]);
        *(us4v*)&dst[(size_t)(dst_row_base + blockIdx.z * 64 + c0 + c) * dst_ld + r0 + r4] = o;
    }
}

// ---------------------------------------------------------------------------
// QKV GEMM: C = xb[8192x1024] * Wt^T  (Wt is [3072 n][1024 k] bf16).
// 128x128 tile, BK=32, 4 waves (2x2), 16 MFMA/K-step, global_load_lds staging.
// Epilogue scatters to q (scaled 0.125), k as [bh][t][e], v transposed [bh][e][t].
// ---------------------------------------------------------------------------
__global__ __launch_bounds__(256) void qkv_mfma(
        const unsigned short* __restrict__ A,   // xb
        const unsigned short* __restrict__ Bt,  // Wt [3072][1024]
        unsigned short* __restrict__ qb, unsigned short* __restrict__ kb,
        unsigned short* __restrict__ vT) {
    __shared__ unsigned short As[128 * 32];
    __shared__ unsigned short Bs[128 * 32];
    const int tid = threadIdx.x;
    const int lane = tid & 63, wid = tid >> 6;
    const int l16 = lane & 15, l4 = lane >> 4;
    const int wr = wid >> 1, wc = wid & 1;
    const size_t m0 = blockIdx.y * 128, n0 = blockIdx.x * 128;

    f32x4 acc[4][4] = {};
    for (int k0 = 0; k0 < D_; k0 += 32) {
        #pragma unroll
        for (int c = 0; c < 2; ++c) {
            int idx = c * 256 + tid;             // 0..511
            int row = idx >> 2, q = idx & 3;
            gl_lds16(A  + (m0 + row) * (size_t)D_ + k0 + q * 8, &As[row * 32 + q * 8]);
            gl_lds16(Bt + (n0 + row) * (size_t)D_ + k0 + q * 8, &Bs[row * 32 + q * 8]);
        }
        __syncthreads();
        short8 a[4], b[4];
        #pragma unroll
        for (int i = 0; i < 4; ++i)
            a[i] = *(const short8*)&As[(wr * 64 + i * 16 + l16) * 32 + l4 * 8];
        #pragma unroll
        for (int j = 0; j < 4; ++j)
            b[j] = *(const short8*)&Bs[(wc * 64 + j * 16 + l16) * 32 + l4 * 8];
        #pragma unroll
        for (int i = 0; i < 4; ++i)
            #pragma unroll
            for (int j = 0; j < 4; ++j)
                acc[i][j] = MFMA16(a[i], b[j], acc[i][j]);
        __syncthreads();
    }

    #pragma unroll
    for (int j = 0; j < 4; ++j) {
        int n = (int)n0 + wc * 64 + j * 16 + l16;
        int sel = n >> 10, h = (n >> 6) & (H_ - 1), e = n & 63;
        float scale = (sel == 0) ? 0.125f : 1.0f;
        #pragma unroll
        for (int i = 0; i < 4; ++i) {
            #pragma unroll
            for (int r = 0; r < 4; ++r) {
                int m = (int)m0 + wr * 64 + i * 16 + l4 * 4 + r;
                int b_ = m >> 11, t = m & (T_ - 1);
                unsigned short val = f2bf(acc[i][j][r] * scale);
                if (sel == 0)
                    qb[((size_t)(b_ * H_ + h) * T_ + t) * HD_ + e] = val;
                else if (sel == 1)
                    kb[((size_t)(b_ * H_ + h) * T_ + t) * HD_ + e] = val;
                else
                    vT[((size_t)(b_ * H_ + h) * HD_ + e) * T_ + t] = val;
            }
        }
    }
}

// ---------------------------------------------------------------------------
// Causal flash attention, bf16 MFMA. grid=(T/64, BH). 4 waves x 16 q-rows.
// K, V^T read directly from global (L1/L2-resident). P relayout via per-wave LDS.
// ---------------------------------------------------------------------------
__global__ __launch_bounds__(256) void attn_mfma(
        const unsigned short* __restrict__ qb, const unsigned short* __restrict__ kb,
        const unsigned short* __restrict__ vT, unsigned short* __restrict__ Ob) {
    __shared__ unsigned short Plds[4][16][80];   // pad 80: 16B-aligned rows
    const int bh = blockIdx.y;
    const int b = bh >> 4, h = bh & (H_ - 1);
    const int t0 = blockIdx.x * 64;
    const int lane = threadIdx.x & 63, wid = threadIdx.x >> 6;
    const int l16 = lane & 15, l4 = lane >> 4;

    const unsigned short* kbase = kb + (size_t)bh * T_ * HD_;
    const unsigned short* vbase = vT + (size_t)bh * HD_ * T_;

    short8 qf0, qf1;
    {
        const unsigned short* qrow = qb + ((size_t)bh * T_ + t0 + wid * 16 + l16) * HD_;
        qf0 = *(const short8*)(qrow + l4 * 8);
        qf1 = *(const short8*)(qrow + 32 + l4 * 8);
    }

    f32x4 o[4] = {};
    float mrow[4], lrow[4];
    #pragma unroll
    for (int r = 0; r < 4; ++r) { mrow[r] = -__builtin_inff(); lrow[r] = 0.f; }

    for (int jt = 0; jt <= t0; jt += 64) {
        // ---- S = Q K^T (16 x 64) ----
        f32x4 s[4];
        #pragma unroll
        for (int sc = 0; sc < 4; ++sc) {
            const unsigned short* krow = kbase + (size_t)(jt + sc * 16 + l16) * HD_;
            short8 kf0 = *(const short8*)(krow + l4 * 8);
            short8 kf1 = *(const short8*)(krow + 32 + l4 * 8);
            f32x4 z = {0.f, 0.f, 0.f, 0.f};
            z = MFMA16(qf0, kf0, z);
            z = MFMA16(qf1, kf1, z);
            s[sc] = z;
        }
        // ---- causal mask (diagonal tile only) ----
        if (jt == t0) {
            int trb = wid * 16 + l4 * 4;         // local row base
            #pragma unroll
            for (int sc = 0; sc < 4; ++sc) {
                int sl = sc * 16 + l16;
                #pragma unroll
                for (int r = 0; r < 4; ++r)
                    if (sl > trb + r) s[sc][r] = -1e30f;
            }
        }
        // ---- online softmax (rows spread over 16-lane groups) ----
        float corr[4], psum[4];
        #pragma unroll
        for (int r = 0; r < 4; ++r) {
            float v = fmaxf(fmaxf(s[0][r], s[1][r]), fmaxf(s[2][r], s[3][r]));
            v = fmaxf(v, __shfl_xor(v, 1));
            v = fmaxf(v, __shfl_xor(v, 2));
            v = fmaxf(v, __shfl_xor(v, 4));
            v = fmaxf(v, __shfl_xor(v, 8));
            float mn = fmaxf(mrow[r], v);
            corr[r] = __expf(mrow[r] - mn);
            mrow[r] = mn;
            psum[r] = 0.f;
        }
        #pragma unroll
        for (int sc = 0; sc < 4; ++sc)
            #pragma unroll
            for (int r = 0; r < 4; ++r) {
                float p = __expf(s[sc][r] - mrow[r]);
                psum[r] += p;
                Plds[wid][l4 * 4 + r][sc * 16 + l16] = f2bf(p);
            }
        #pragma unroll
        for (int r = 0; r < 4; ++r) {
            float v = psum[r];
            v += __shfl_xor(v, 1);
            v += __shfl_xor(v, 2);
            v += __shfl_xor(v, 4);
            v += __shfl_xor(v, 8);
            lrow[r] = lrow[r] * corr[r] + v;
        }
        #pragma unroll
        for (int ec = 0; ec < 4; ++ec)
            #pragma unroll
            for (int r = 0; r < 4; ++r) o[ec][r] *= corr[r];
        // wave-internal: P writes must land before P-fragment reads
        asm volatile("s_waitcnt lgkmcnt(0)" ::: "memory");
        // ---- O += P V ----
        #pragma unroll
        for (int kc = 0; kc < 2; ++kc) {
            short8 pf = *(const short8*)&Plds[wid][l16][kc * 32 + l4 * 8];
            #pragma unroll
            for (int ec = 0; ec < 4; ++ec) {
                const unsigned short* vrow = vbase + (size_t)(ec * 16 + l16) * T_ + jt + kc * 32 + l4 * 8;
                short8 vf = *(const short8*)vrow;
                o[ec] = MFMA16(pf, vf, o[ec]);
            }
        }
    }

    #pragma unroll
    for (int r = 0; r < 4; ++r) {
        float inv = 1.f / lrow[r];
        int t = t0 + wid * 16 + l4 * 4 + r;
        unsigned short* orow = Ob + ((size_t)(b * T_ + t)) * D_ + h * HD_;
        #pragma unroll
        for (int ec = 0; ec < 4; ++ec)
            orow[ec * 16 + l16] = f2bf(o[ec][r] * inv);
    }
}

// ---------------------------------------------------------------------------
// Output projection: out = Ob[8192x1024] * Wpt^T + bp, fp32 out.
// ---------------------------------------------------------------------------
__global__ __launch_bounds__(256) void proj_mfma(
        const unsigned short* __restrict__ A,    // Ob
        const unsigned short* __restrict__ Bt,   // Wpt [1024 n][1024 k]
        const float* __restrict__ bp, float* __restrict__ out) {
    __shared__ unsigned short As[128 * 32];
    __shared__ unsigned short Bs[128 * 32];
    const int tid = threadIdx.x;
    const int lane = tid & 63, wid = tid >> 6;
    const int l16 = lane & 15, l4 = lane >> 4;
    const int wr = wid >> 1, wc = wid & 1;
    const size_t m0 = blockIdx.y * 128, n0 = blockIdx.x * 128;

    f32x4 acc[4][4] = {};
    for (int k0 = 0; k0 < D_; k0 += 32) {
        #pragma unroll
        for (int c = 0; c < 2; ++c) {
            int idx = c * 256 + tid;
            int row = idx >> 2, q = idx & 3;
            gl_lds16(A  + (m0 + row) * (size_t)D_ + k0 + q * 8, &As[row * 32 + q * 8]);
            gl_lds16(Bt + (n0 + row) * (size_t)D_ + k0 + q * 8, &Bs[row * 32 + q * 8]);
        }
        __syncthreads();
        short8 a[4], b[4];
        #pragma unroll
        for (int i = 0; i < 4; ++i)
            a[i] = *(const short8*)&As[(wr * 64 + i * 16 + l16) * 32 + l4 * 8];
        #pragma unroll
        for (int j = 0; j < 4; ++j)
            b[j] = *(const short8*)&Bs[(wc * 64 + j * 16 + l16) * 32 + l4 * 8];
        #pragma unroll
        for (int i = 0; i < 4; ++i)
            #pragma unroll
            for (int j = 0; j < 4; ++j)
                acc[i][j] = MFMA16(a[i], b[j], acc[i][j]);
        __syncthreads();
    }

    #pragma unroll
    for (int j = 0; j < 4; ++j) {
        int n = (int)n0 + wc * 64 + j * 16 + l16;
        float bias = bp[n];
        #pragma unroll
        for (int i = 0; i < 4; ++i)
            #pragma unroll
            for (int r = 0; r < 4; ++r) {
                int m = (int)m0 + wr * 64 + i * 16 + l4 * 4 + r;
                out[(size_t)m * D_ + n] = acc[i][j][r] + bias;
            }
    }
}

// ---------------------------------------------------------------------------
extern "C" void kernel_launch(void* const* d_in, const int* in_sizes, int n_in,
                              void* d_out, int out_size, void* d_ws, size_t ws_size,
                              hipStream_t stream) {
    const float* x  = (const float*)d_in[0];
    const float* Wq = (const float*)d_in[1];
    const float* Wk = (const float*)d_in[2];
    const float* Wv = (const float*)d_in[3];
    const float* Wp = (const float*)d_in[4];
    const float* bp = (const float*)d_in[5];
    float* out = (float*)d_out;

    char* w = (char*)d_ws;
    unsigned short* xb  = (unsigned short*)w; w += (size_t)M_ * D_ * 2;          // 16.8 MB
    unsigned short* Wt  = (unsigned short*)w; w += (size_t)3 * D_ * D_ * 2;      // 6.3 MB (3072x1024)
    unsigned short* Wpt = (unsigned short*)w; w += (size_t)D_ * D_ * 2;          // 2.1 MB
    unsigned short* qb  = (unsigned short*)w; w += (size_t)BH_ * T_ * HD_ * 2;   // 16.8 MB
    unsigned short* kb  = (unsigned short*)w; w += (size_t)BH_ * T_ * HD_ * 2;
    unsigned short* vT  = (unsigned short*)w; w += (size_t)BH_ * T_ * HD_ * 2;
    unsigned short* Ob  = (unsigned short*)w; w += (size_t)M_ * D_ * 2;

    // converts
    cvt_x<<<dim3((M_ * D_ / 4 + 255) / 256), 256, 0, stream>>>(x, xb, M_ * D_ / 4);
    tcvt<<<dim3(16, 1, 16), 256, 0, stream>>>(Wq, Wt, HD_, (long)D_ * HD_, 0,        D_);
    tcvt<<<dim3(16, 1, 16), 256, 0, stream>>>(Wk, Wt, HD_, (long)D_ * HD_, 1024,     D_);
    tcvt<<<dim3(16, 1, 16), 256, 0, stream>>>(Wv, Wt, HD_, (long)D_ * HD_, 2048,     D_);
    tcvt<<<dim3(16, 16, 1), 256, 0, stream>>>(Wp, Wpt, D_, 0,              0,        D_);

    // QKV projection
    qkv_mfma<<<dim3(24, 64), 256, 0, stream>>>(xb, Wt, qb, kb, vT);
    // attention
    attn_mfma<<<dim3(T_ / 64, BH_), 256, 0, stream>>>(qb, kb, vT, Ob);
    // output projection
    proj_mfma<<<dim3(8, 64), 256, 0, stream>>>(Ob, Wpt, bp, out);
}

// Round 3
// 271.046 us; speedup vs baseline: 7.9297x; 2.2080x over previous
//
#include <hip/hip_runtime.h>
#include <hip/hip_bf16.h>

#define B_  4
#define T_  2048
#define D_  1024
#define H_  16
#define HD_ 64
#define M_  (B_ * T_)          // 8192 rows
#define BH_ (B_ * H_)          // 64

typedef __attribute__((ext_vector_type(8))) short   short8;   // 8 x bf16 (4 VGPR)
typedef __attribute__((ext_vector_type(4))) float   f32x4;
typedef __attribute__((ext_vector_type(4))) unsigned short us4v;

#define MFMA16(a, b, c) __builtin_amdgcn_mfma_f32_16x16x32_bf16((a), (b), (c), 0, 0, 0)

__device__ __forceinline__ unsigned short f2bf(float f) {
    union { float f; unsigned u; } v; v.f = f;
    unsigned r = v.u + 0x7fffu + ((v.u >> 16) & 1u);   // round-nearest-even
    return (unsigned short)(r >> 16);
}

__device__ __forceinline__ void gl_lds16(const void* g, void* l) {
    __builtin_amdgcn_global_load_lds(
        (const __attribute__((address_space(1))) void*)g,
        (__attribute__((address_space(3))) void*)l, 16, 0, 0);
}

// ---------------------------------------------------------------------------
__global__ __launch_bounds__(256) void cvt_x(const float* __restrict__ x,
                                             unsigned short* __restrict__ xb, int n4) {
    int i = blockIdx.x * 256 + threadIdx.x;
    if (i < n4) {
        float4 v = ((const float4*)x)[i];
        us4v o;
        o[0] = f2bf(v.x); o[1] = f2bf(v.y); o[2] = f2bf(v.z); o[3] = f2bf(v.w);
        ((us4v*)xb)[i] = o;
    }
}

// ---------------------------------------------------------------------------
__global__ __launch_bounds__(256) void tcvt(const float* __restrict__ src,
                                            unsigned short* __restrict__ dst,
                                            int src_ld, long src_z_str,
                                            int dst_row_base, int dst_ld) {
    __shared__ float tile[64][65];
    const float* s = src + (size_t)blockIdx.z * src_z_str;
    int r0 = blockIdx.x * 64, c0 = blockIdx.y * 64;
    int tid = threadIdx.x;
    #pragma unroll
    for (int i = 0; i < 4; ++i) {
        int idx4 = i * 256 + tid;
        int r = idx4 >> 4, c4 = (idx4 & 15) * 4;
        float4 v = *(const float4*)&s[(size_t)(r0 + r) * src_ld + c0 + c4];
        tile[r][c4 + 0] = v.x; tile[r][c4 + 1] = v.y;
        tile[r][c4 + 2] = v.z; tile[r][c4 + 3] = v.w;
    }
    __syncthreads();
    #pragma unroll
    for (int i = 0; i < 4; ++i) {
        int idx4 = i * 256 + tid;
        int c = idx4 >> 4, r4 = (idx4 & 15) * 4;
        us4v o;
        o[0] = f2bf(tile[r4 + 0][c]); o[1] = f2bf(tile[r4 + 1][c]);
        o[2] = f2bf(tile[r4 + 2][c]); o[3] = f2bf(tile[r4 + 3][c]);
        *(us4v*)&dst[(size_t)(dst_row_base + blockIdx.z * 64 + c0 + c) * dst_ld + r0 + r4] = o;
    }
}

// ---------------------------------------------------------------------------
// QKV GEMM (unchanged from round 2)
// ---------------------------------------------------------------------------
__global__ __launch_bounds__(256) void qkv_mfma(
        const unsigned short* __restrict__ A,
        const unsigned short* __restrict__ Bt,
        unsigned short* __restrict__ qb, unsigned short* __restrict__ kb,
        unsigned short* __restrict__ vT) {
    __shared__ unsigned short As[128 * 32];
    __shared__ unsigned short Bs[128 * 32];
    const int tid = threadIdx.x;
    const int lane = tid & 63, wid = tid >> 6;
    const int l16 = lane & 15, l4 = lane >> 4;
    const int wr = wid >> 1, wc = wid & 1;
    const size_t m0 = blockIdx.y * 128, n0 = blockIdx.x * 128;

    f32x4 acc[4][4] = {};
    for (int k0 = 0; k0 < D_; k0 += 32) {
        #pragma unroll
        for (int c = 0; c < 2; ++c) {
            int idx = c * 256 + tid;
            int row = idx >> 2, q = idx & 3;
            gl_lds16(A  + (m0 + row) * (size_t)D_ + k0 + q * 8, &As[row * 32 + q * 8]);
            gl_lds16(Bt + (n0 + row) * (size_t)D_ + k0 + q * 8, &Bs[row * 32 + q * 8]);
        }
        __syncthreads();
        short8 a[4], b[4];
        #pragma unroll
        for (int i = 0; i < 4; ++i)
            a[i] = *(const short8*)&As[(wr * 64 + i * 16 + l16) * 32 + l4 * 8];
        #pragma unroll
        for (int j = 0; j < 4; ++j)
            b[j] = *(const short8*)&Bs[(wc * 64 + j * 16 + l16) * 32 + l4 * 8];
        #pragma unroll
        for (int i = 0; i < 4; ++i)
            #pragma unroll
            for (int j = 0; j < 4; ++j)
                acc[i][j] = MFMA16(a[i], b[j], acc[i][j]);
        __syncthreads();
    }

    #pragma unroll
    for (int j = 0; j < 4; ++j) {
        int n = (int)n0 + wc * 64 + j * 16 + l16;
        int sel = n >> 10, h = (n >> 6) & (H_ - 1), e = n & 63;
        float scale = (sel == 0) ? 0.125f : 1.0f;
        #pragma unroll
        for (int i = 0; i < 4; ++i) {
            #pragma unroll
            for (int r = 0; r < 4; ++r) {
                int m = (int)m0 + wr * 64 + i * 16 + l4 * 4 + r;
                int b_ = m >> 11, t = m & (T_ - 1);
                unsigned short val = f2bf(acc[i][j][r] * scale);
                if (sel == 0)
                    qb[((size_t)(b_ * H_ + h) * T_ + t) * HD_ + e] = val;
                else if (sel == 1)
                    kb[((size_t)(b_ * H_ + h) * T_ + t) * HD_ + e] = val;
                else
                    vT[((size_t)(b_ * H_ + h) * HD_ + e) * T_ + t] = val;
            }
        }
    }
}

// ---------------------------------------------------------------------------
// Attention v3: balanced tile-pairing + LDS-staged double-buffered K/V with
// XOR swizzle (pre-swizzled global source, swizzled reads) + XCD-local bh.
// Block handles q-tiles (pair, 31-pair) of one bh; 4 waves x 16 q-rows each.
// ---------------------------------------------------------------------------
__device__ __forceinline__ void stage_kv(const unsigned short* kbase,
                                         const unsigned short* vbase,
                                         unsigned short* KsBuf, unsigned short* VsBuf,
                                         int jt, int wid, int lane) {
    int s = lane & 7, rl = lane >> 3;          // slot 0..7, row-in-chunk 0..7
    int cchunk = s ^ rl;                       // pre-swizzled source col-chunk
    #pragma unroll
    for (int cc = 0; cc < 2; ++cc) {
        int chunk = cc * 4 + wid;
        int r = chunk * 8 + rl;                // tile row 0..63
        gl_lds16(kbase + (size_t)(jt + r) * HD_ + cchunk * 8,
                 KsBuf + chunk * 512 + lane * 8);
        gl_lds16(vbase + (size_t)r * T_ + jt + cchunk * 8,
                 VsBuf + chunk * 512 + lane * 8);
    }
}

__device__ __forceinline__ void attn_tile_step(
        const unsigned short* Ksb, const unsigned short* Vsb, unsigned short* Pw,
        short8 qf0, short8 qf1, int diag, int rowbase, int l16, int l4,
        f32x4 (&o)[4], float (&m)[4], float (&l)[4]) {
    f32x4 s[4];
    const int swz = l16 & 7;
    #pragma unroll
    for (int sc = 0; sc < 4; ++sc) {
        int row = sc * 16 + l16;
        int sl0 = l4 ^ swz;
        short8 kf0 = *(const short8*)&Ksb[row * 64 + sl0 * 8];
        short8 kf1 = *(const short8*)&Ksb[row * 64 + (sl0 ^ 4) * 8];
        f32x4 z = {0.f, 0.f, 0.f, 0.f};
        z = MFMA16(qf0, kf0, z);
        z = MFMA16(qf1, kf1, z);
        s[sc] = z;
    }
    if (diag) {
        #pragma unroll
        for (int sc = 0; sc < 4; ++sc) {
            int col = sc * 16 + l16;
            #pragma unroll
            for (int r = 0; r < 4; ++r)
                if (col > rowbase + r) s[sc][r] = -1e30f;
        }
    }
    float corr[4];
    #pragma unroll
    for (int r = 0; r < 4; ++r) {
        float v = fmaxf(fmaxf(s[0][r], s[1][r]), fmaxf(s[2][r], s[3][r]));
        v = fmaxf(v, __shfl_xor(v, 1));
        v = fmaxf(v, __shfl_xor(v, 2));
        v = fmaxf(v, __shfl_xor(v, 4));
        v = fmaxf(v, __shfl_xor(v, 8));
        float mn = fmaxf(m[r], v);
        corr[r] = __expf(m[r] - mn);
        m[r] = mn;
    }
    float psum[4] = {0.f, 0.f, 0.f, 0.f};
    #pragma unroll
    for (int sc = 0; sc < 4; ++sc) {
        int col = sc * 16 + l16;
        #pragma unroll
        for (int r = 0; r < 4; ++r) {
            float p = __expf(s[sc][r] - m[r]);
            psum[r] += p;
            int row = l4 * 4 + r;
            Pw[row * 64 + (col ^ ((row & 7) << 3))] = f2bf(p);
        }
    }
    #pragma unroll
    for (int r = 0; r < 4; ++r) {
        float v = psum[r];
        v += __shfl_xor(v, 1);
        v += __shfl_xor(v, 2);
        v += __shfl_xor(v, 4);
        v += __shfl_xor(v, 8);
        l[r] = l[r] * corr[r] + v;
    }
    #pragma unroll
    for (int ec = 0; ec < 4; ++ec)
        #pragma unroll
        for (int r = 0; r < 4; ++r) o[ec][r] *= corr[r];
    asm volatile("s_waitcnt lgkmcnt(0)" ::: "memory");
    __builtin_amdgcn_sched_barrier(0);
    #pragma unroll
    for (int kc = 0; kc < 2; ++kc) {
        int chunk = kc * 4 + l4;
        short8 pf = *(const short8*)&Pw[l16 * 64 + ((chunk ^ swz) * 8)];
        #pragma unroll
        for (int ec = 0; ec < 4; ++ec) {
            int vrow = ec * 16 + l16;
            short8 vf = *(const short8*)&Vsb[vrow * 64 + ((chunk ^ swz) * 8)];
            o[ec] = MFMA16(pf, vf, o[ec]);
        }
    }
}

__global__ __launch_bounds__(256) void attn2(
        const unsigned short* __restrict__ qb, const unsigned short* __restrict__ kb,
        const unsigned short* __restrict__ vT, unsigned short* __restrict__ Ob) {
    __shared__ unsigned short Ks[2][64 * 64];
    __shared__ unsigned short Vs[2][64 * 64];
    __shared__ unsigned short Pl[4][16 * 64];

    const int blk = blockIdx.x;                 // 0..1023
    const int bh = (blk & 7) + 8 * ((blk >> 3) & 7);   // XCD-local bh
    const int pair = blk >> 6;                  // 0..15
    const int iA = pair, iB = 31 - pair;
    const int t0A = iA * 64, t0B = iB * 64;
    const int b = bh >> 4, h = bh & (H_ - 1);

    const int lane = threadIdx.x & 63, wid = threadIdx.x >> 6;
    const int l16 = lane & 15, l4 = lane >> 4;
    const int rowbase = wid * 16 + l4 * 4;

    const unsigned short* kbase = kb + (size_t)bh * T_ * HD_;
    const unsigned short* vbase = vT + (size_t)bh * HD_ * T_;
    const unsigned short* qbase = qb + (size_t)bh * T_ * HD_;

    short8 qA0, qA1, qB0, qB1;
    {
        const unsigned short* qr = qbase + (size_t)(t0A + wid * 16 + l16) * HD_;
        qA0 = *(const short8*)(qr + l4 * 8);
        qA1 = *(const short8*)(qr + 32 + l4 * 8);
        qr = qbase + (size_t)(t0B + wid * 16 + l16) * HD_;
        qB0 = *(const short8*)(qr + l4 * 8);
        qB1 = *(const short8*)(qr + 32 + l4 * 8);
    }

    f32x4 oA[4] = {}, oB[4] = {};
    float mA[4], lA[4], mB[4], lB[4];
    #pragma unroll
    for (int r = 0; r < 4; ++r) {
        mA[r] = -__builtin_inff(); lA[r] = 0.f;
        mB[r] = -__builtin_inff(); lB[r] = 0.f;
    }

    stage_kv(kbase, vbase, Ks[0], Vs[0], 0, wid, lane);
    asm volatile("s_waitcnt vmcnt(0)" ::: "memory");
    __syncthreads();

    for (int it = 0; it <= iB; ++it) {
        const int cur = it & 1;
        if (it < iB)
            stage_kv(kbase, vbase, Ks[cur ^ 1], Vs[cur ^ 1], (it + 1) * 64, wid, lane);
        if (it <= iA)
            attn_tile_step(Ks[cur], Vs[cur], Pl[wid], qA0, qA1, it == iA,
                           rowbase, l16, l4, oA, mA, lA);
        attn_tile_step(Ks[cur], Vs[cur], Pl[wid], qB0, qB1, it == iB,
                       rowbase, l16, l4, oB, mB, lB);
        asm volatile("s_waitcnt vmcnt(0)" ::: "memory");
        __syncthreads();
    }

    #pragma unroll
    for (int r = 0; r < 4; ++r) {
        float inv = 1.f / lA[r];
        int t = t0A + wid * 16 + l4 * 4 + r;
        unsigned short* orow = Ob + ((size_t)(b * T_ + t)) * D_ + h * HD_;
        #pragma unroll
        for (int ec = 0; ec < 4; ++ec)
            orow[ec * 16 + l16] = f2bf(oA[ec][r] * inv);
    }
    #pragma unroll
    for (int r = 0; r < 4; ++r) {
        float inv = 1.f / lB[r];
        int t = t0B + wid * 16 + l4 * 4 + r;
        unsigned short* orow = Ob + ((size_t)(b * T_ + t)) * D_ + h * HD_;
        #pragma unroll
        for (int ec = 0; ec < 4; ++ec)
            orow[ec * 16 + l16] = f2bf(oB[ec][r] * inv);
    }
}

// ---------------------------------------------------------------------------
// Output projection (unchanged from round 2)
// ---------------------------------------------------------------------------
__global__ __launch_bounds__(256) void proj_mfma(
        const unsigned short* __restrict__ A,
        const unsigned short* __restrict__ Bt,
        const float* __restrict__ bp, float* __restrict__ out) {
    __shared__ unsigned short As[128 * 32];
    __shared__ unsigned short Bs[128 * 32];
    const int tid = threadIdx.x;
    const int lane = tid & 63, wid = tid >> 6;
    const int l16 = lane & 15, l4 = lane >> 4;
    const int wr = wid >> 1, wc = wid & 1;
    const size_t m0 = blockIdx.y * 128, n0 = blockIdx.x * 128;

    f32x4 acc[4][4] = {};
    for (int k0 = 0; k0 < D_; k0 += 32) {
        #pragma unroll
        for (int c = 0; c < 2; ++c) {
            int idx = c * 256 + tid;
            int row = idx >> 2, q = idx & 3;
            gl_lds16(A  + (m0 + row) * (size_t)D_ + k0 + q * 8, &As[row * 32 + q * 8]);
            gl_lds16(Bt + (n0 + row) * (size_t)D_ + k0 + q * 8, &Bs[row * 32 + q * 8]);
        }
        __syncthreads();
        short8 a[4], b[4];
        #pragma unroll
        for (int i = 0; i < 4; ++i)
            a[i] = *(const short8*)&As[(wr * 64 + i * 16 + l16) * 32 + l4 * 8];
        #pragma unroll
        for (int j = 0; j < 4; ++j)
            b[j] = *(const short8*)&Bs[(wc * 64 + j * 16 + l16) * 32 + l4 * 8];
        #pragma unroll
        for (int i = 0; i < 4; ++i)
            #pragma unroll
            for (int j = 0; j < 4; ++j)
                acc[i][j] = MFMA16(a[i], b[j], acc[i][j]);
        __syncthreads();
    }

    #pragma unroll
    for (int j = 0; j < 4; ++j) {
        int n = (int)n0 + wc * 64 + j * 16 + l16;
        float bias = bp[n];
        #pragma unroll
        for (int i = 0; i < 4; ++i)
            #pragma unroll
            for (int r = 0; r < 4; ++r) {
                int m = (int)m0 + wr * 64 + i * 16 + l4 * 4 + r;
                out[(size_t)m * D_ + n] = acc[i][j][r] + bias;
            }
    }
}

// ---------------------------------------------------------------------------
extern "C" void kernel_launch(void* const* d_in, const int* in_sizes, int n_in,
                              void* d_out, int out_size, void* d_ws, size_t ws_size,
                              hipStream_t stream) {
    const float* x  = (const float*)d_in[0];
    const float* Wq = (const float*)d_in[1];
    const float* Wk = (const float*)d_in[2];
    const float* Wv = (const float*)d_in[3];
    const float* Wp = (const float*)d_in[4];
    const float* bp = (const float*)d_in[5];
    float* out = (float*)d_out;

    char* w = (char*)d_ws;
    unsigned short* xb  = (unsigned short*)w; w += (size_t)M_ * D_ * 2;
    unsigned short* Wt  = (unsigned short*)w; w += (size_t)3 * D_ * D_ * 2;
    unsigned short* Wpt = (unsigned short*)w; w += (size_t)D_ * D_ * 2;
    unsigned short* qb  = (unsigned short*)w; w += (size_t)BH_ * T_ * HD_ * 2;
    unsigned short* kb  = (unsigned short*)w; w += (size_t)BH_ * T_ * HD_ * 2;
    unsigned short* vT  = (unsigned short*)w; w += (size_t)BH_ * T_ * HD_ * 2;
    unsigned short* Ob  = (unsigned short*)w; w += (size_t)M_ * D_ * 2;

    cvt_x<<<dim3((M_ * D_ / 4 + 255) / 256), 256, 0, stream>>>(x, xb, M_ * D_ / 4);
    tcvt<<<dim3(16, 1, 16), 256, 0, stream>>>(Wq, Wt, HD_, (long)D_ * HD_, 0,    D_);
    tcvt<<<dim3(16, 1, 16), 256, 0, stream>>>(Wk, Wt, HD_, (long)D_ * HD_, 1024, D_);
    tcvt<<<dim3(16, 1, 16), 256, 0, stream>>>(Wv, Wt, HD_, (long)D_ * HD_, 2048, D_);
    tcvt<<<dim3(16, 16, 1), 256, 0, stream>>>(Wp, Wpt, D_, 0,              0,    D_);

    qkv_mfma<<<dim3(24, 64), 256, 0, stream>>>(xb, Wt, qb, kb, vT);
    attn2<<<dim3(1024), 256, 0, stream>>>(qb, kb, vT, Ob);
    proj_mfma<<<dim3(8, 64), 256, 0, stream>>>(Ob, Wpt, bp, out);
}

// Round 4
// 229.347 us; speedup vs baseline: 9.3714x; 1.1818x over previous
//
#include <hip/hip_runtime.h>
#include <hip/hip_bf16.h>

#define B_  4
#define T_  2048
#define D_  1024
#define H_  16
#define HD_ 64
#define M_  (B_ * T_)          // 8192 rows
#define BH_ (B_ * H_)          // 64

typedef __attribute__((ext_vector_type(8))) short   short8;   // 8 x bf16 (4 VGPR)
typedef __attribute__((ext_vector_type(4))) float   f32x4;
typedef __attribute__((ext_vector_type(4))) unsigned short us4v;

#define MFMA16(a, b, c) __builtin_amdgcn_mfma_f32_16x16x32_bf16((a), (b), (c), 0, 0, 0)

__device__ __forceinline__ unsigned short f2bf(float f) {
    union { float f; unsigned u; } v; v.f = f;
    unsigned r = v.u + 0x7fffu + ((v.u >> 16) & 1u);   // round-nearest-even
    return (unsigned short)(r >> 16);
}

__device__ __forceinline__ float exp2_fast(float x) {
    float r; asm("v_exp_f32 %0, %1" : "=v"(r) : "v"(x)); return r;
}
__device__ __forceinline__ unsigned cvt_pk_bf16(float lo, float hi) {
    unsigned r; asm("v_cvt_pk_bf16_f32 %0, %1, %2" : "=v"(r) : "v"(lo), "v"(hi)); return r;
}

__device__ __forceinline__ void gl_lds16(const void* g, void* l) {
    __builtin_amdgcn_global_load_lds(
        (const __attribute__((address_space(1))) void*)g,
        (__attribute__((address_space(3))) void*)l, 16, 0, 0);
}

// ---------------------------------------------------------------------------
__global__ __launch_bounds__(256) void cvt_x(const float* __restrict__ x,
                                             unsigned short* __restrict__ xb, int n4) {
    int i = blockIdx.x * 256 + threadIdx.x;
    if (i < n4) {
        float4 v = ((const float4*)x)[i];
        us4v o;
        o[0] = f2bf(v.x); o[1] = f2bf(v.y); o[2] = f2bf(v.z); o[3] = f2bf(v.w);
        ((us4v*)xb)[i] = o;
    }
}

// ---------------------------------------------------------------------------
// Transpose+convert the three head-projection weights in one launch.
// grid.z in [0,48): sel = z>>4 (q/k/v), head = z&15. Each block: 64x64 tile.
// dst row = sel*1024 + head*64 + e; dst col = k; dst ld = D_.
// ---------------------------------------------------------------------------
__global__ __launch_bounds__(256) void tcvt_qkv(
        const float* __restrict__ Wq, const float* __restrict__ Wk,
        const float* __restrict__ Wv, unsigned short* __restrict__ dst) {
    __shared__ float tile[64][65];
    int z = blockIdx.z;
    int sel = z >> 4, head = z & 15;
    const float* s = (sel == 0 ? Wq : (sel == 1 ? Wk : Wv)) + (size_t)head * D_ * HD_;
    int r0 = blockIdx.x * 64;               // k-range
    int tid = threadIdx.x;
    #pragma unroll
    for (int i = 0; i < 4; ++i) {
        int idx4 = i * 256 + tid;
        int r = idx4 >> 4, c4 = (idx4 & 15) * 4;
        float4 v = *(const float4*)&s[(size_t)(r0 + r) * HD_ + c4];
        tile[r][c4 + 0] = v.x; tile[r][c4 + 1] = v.y;
        tile[r][c4 + 2] = v.z; tile[r][c4 + 3] = v.w;
    }
    __syncthreads();
    #pragma unroll
    for (int i = 0; i < 4; ++i) {
        int idx4 = i * 256 + tid;
        int c = idx4 >> 4, r4 = (idx4 & 15) * 4;
        us4v o;
        o[0] = f2bf(tile[r4 + 0][c]); o[1] = f2bf(tile[r4 + 1][c]);
        o[2] = f2bf(tile[r4 + 2][c]); o[3] = f2bf(tile[r4 + 3][c]);
        *(us4v*)&dst[(size_t)(sel * 1024 + head * 64 + c) * D_ + r0 + r4] = o;
    }
}

// ---------------------------------------------------------------------------
__global__ __launch_bounds__(256) void tcvt(const float* __restrict__ src,
                                            unsigned short* __restrict__ dst,
                                            int src_ld, long src_z_str,
                                            int dst_row_base, int dst_ld) {
    __shared__ float tile[64][65];
    const float* s = src + (size_t)blockIdx.z * src_z_str;
    int r0 = blockIdx.x * 64, c0 = blockIdx.y * 64;
    int tid = threadIdx.x;
    #pragma unroll
    for (int i = 0; i < 4; ++i) {
        int idx4 = i * 256 + tid;
        int r = idx4 >> 4, c4 = (idx4 & 15) * 4;
        float4 v = *(const float4*)&s[(size_t)(r0 + r) * src_ld + c0 + c4];
        tile[r][c4 + 0] = v.x; tile[r][c4 + 1] = v.y;
        tile[r][c4 + 2] = v.z; tile[r][c4 + 3] = v.w;
    }
    __syncthreads();
    #pragma unroll
    for (int i = 0; i < 4; ++i) {
        int idx4 = i * 256 + tid;
        int c = idx4 >> 4, r4 = (idx4 & 15) * 4;
        us4v o;
        o[0] = f2bf(tile[r4 + 0][c]); o[1] = f2bf(tile[r4 + 1][c]);
        o[2] = f2bf(tile[r4 + 2][c]); o[3] = f2bf(tile[r4 + 3][c]);
        *(us4v*)&dst[(size_t)(dst_row_base + blockIdx.z * 64 + c0 + c) * dst_ld + r0 + r4] = o;
    }
}

// ---------------------------------------------------------------------------
// QKV GEMM (q scaled by 0.125*log2(e) so attention softmax runs in exp2 domain)
// ---------------------------------------------------------------------------
__global__ __launch_bounds__(256) void qkv_mfma(
        const unsigned short* __restrict__ A,
        const unsigned short* __restrict__ Bt,
        unsigned short* __restrict__ qb, unsigned short* __restrict__ kb,
        unsigned short* __restrict__ vT) {
    __shared__ unsigned short As[128 * 32];
    __shared__ unsigned short Bs[128 * 32];
    const int tid = threadIdx.x;
    const int lane = tid & 63, wid = tid >> 6;
    const int l16 = lane & 15, l4 = lane >> 4;
    const int wr = wid >> 1, wc = wid & 1;
    const size_t m0 = blockIdx.y * 128, n0 = blockIdx.x * 128;

    f32x4 acc[4][4] = {};
    for (int k0 = 0; k0 < D_; k0 += 32) {
        #pragma unroll
        for (int c = 0; c < 2; ++c) {
            int idx = c * 256 + tid;
            int row = idx >> 2, q = idx & 3;
            gl_lds16(A  + (m0 + row) * (size_t)D_ + k0 + q * 8, &As[row * 32 + q * 8]);
            gl_lds16(Bt + (n0 + row) * (size_t)D_ + k0 + q * 8, &Bs[row * 32 + q * 8]);
        }
        __syncthreads();
        short8 a[4], b[4];
        #pragma unroll
        for (int i = 0; i < 4; ++i)
            a[i] = *(const short8*)&As[(wr * 64 + i * 16 + l16) * 32 + l4 * 8];
        #pragma unroll
        for (int j = 0; j < 4; ++j)
            b[j] = *(const short8*)&Bs[(wc * 64 + j * 16 + l16) * 32 + l4 * 8];
        #pragma unroll
        for (int i = 0; i < 4; ++i)
            #pragma unroll
            for (int j = 0; j < 4; ++j)
                acc[i][j] = MFMA16(a[i], b[j], acc[i][j]);
        __syncthreads();
    }

    #pragma unroll
    for (int j = 0; j < 4; ++j) {
        int n = (int)n0 + wc * 64 + j * 16 + l16;
        int sel = n >> 10, h = (n >> 6) & (H_ - 1), e = n & 63;
        float scale = (sel == 0) ? 0.18033688011112042f : 1.0f;  // 0.125*log2e
        #pragma unroll
        for (int i = 0; i < 4; ++i) {
            #pragma unroll
            for (int r = 0; r < 4; ++r) {
                int m = (int)m0 + wr * 64 + i * 16 + l4 * 4 + r;
                int b_ = m >> 11, t = m & (T_ - 1);
                unsigned short val = f2bf(acc[i][j][r] * scale);
                if (sel == 0)
                    qb[((size_t)(b_ * H_ + h) * T_ + t) * HD_ + e] = val;
                else if (sel == 1)
                    kb[((size_t)(b_ * H_ + h) * T_ + t) * HD_ + e] = val;
                else
                    vT[((size_t)(b_ * H_ + h) * HD_ + e) * T_ + t] = val;
            }
        }
    }
}

// ---------------------------------------------------------------------------
// Attention v4: swapped QK^T (S^T via mfma(K,Q)) -> per-thread row softmax,
// exp2 domain, packed bf16 P via v_cvt_pk_bf16_f32, defer-max rescale.
// ---------------------------------------------------------------------------
__device__ __forceinline__ void stage_kv(const unsigned short* kbase,
                                         const unsigned short* vbase,
                                         unsigned short* KsBuf, unsigned short* VsBuf,
                                         int jt, int wid, int lane) {
    int s = lane & 7, rl = lane >> 3;          // slot 0..7, row-in-chunk 0..7
    int cchunk = s ^ rl;                       // pre-swizzled source col-chunk
    #pragma unroll
    for (int cc = 0; cc < 2; ++cc) {
        int chunk = cc * 4 + wid;
        int r = chunk * 8 + rl;                // tile row 0..63
        gl_lds16(kbase + (size_t)(jt + r) * HD_ + cchunk * 8,
                 KsBuf + chunk * 512 + lane * 8);
        gl_lds16(vbase + (size_t)r * T_ + jt + cchunk * 8,
                 VsBuf + chunk * 512 + lane * 8);
    }
}

__device__ __forceinline__ void attn_tile_step(
        const unsigned short* Ksb, const unsigned short* Vsb, unsigned short* Pw,
        short8 qf0, short8 qf1, int diag, int wid, int l16, int l4,
        f32x4 (&o)[4], float& m, float& l) {
    f32x4 s[4];
    const int swz = l16 & 7;
    #pragma unroll
    for (int sc = 0; sc < 4; ++sc) {
        int row = sc * 16 + l16;
        int sl0 = l4 ^ swz;
        short8 kf0 = *(const short8*)&Ksb[row * 64 + sl0 * 8];
        short8 kf1 = *(const short8*)&Ksb[row * 64 + (sl0 ^ 4) * 8];
        f32x4 z = {0.f, 0.f, 0.f, 0.f};
        z = MFMA16(kf0, qf0, z);            // swapped: S^T[key][query]
        z = MFMA16(kf1, qf1, z);
        s[sc] = z;
    }
    if (diag) {
        int qloc = wid * 16 + l16;
        #pragma unroll
        for (int sc = 0; sc < 4; ++sc) {
            int kb0 = sc * 16 + l4 * 4;
            #pragma unroll
            for (int r = 0; r < 4; ++r)
                if (kb0 + r > qloc) s[sc][r] = -1e30f;
        }
    }
    // this thread holds 16 keys of query l16
    float vmax = s[0][0];
    #pragma unroll
    for (int sc = 0; sc < 4; ++sc)
        #pragma unroll
        for (int r = 0; r < 4; ++r) vmax = fmaxf(vmax, s[sc][r]);
    vmax = fmaxf(vmax, __shfl_xor(vmax, 16));
    vmax = fmaxf(vmax, __shfl_xor(vmax, 32));

    if (!__all(vmax - m <= 8.0f)) {         // defer-max: skip rescale if small growth
        float mn = fmaxf(m, vmax);
        float corr = exp2_fast(m - mn);     // m=-inf -> 0
        m = mn;
        l *= corr;
        #pragma unroll
        for (int r = 0; r < 4; ++r) {
            float cr = __shfl(corr, l4 * 4 + r);
            #pragma unroll
            for (int ec = 0; ec < 4; ++ec) o[ec][r] *= cr;
        }
    }
    float psum = 0.f;
    char* prow = (char*)Pw + l16 * 128;
    #pragma unroll
    for (int sc = 0; sc < 4; ++sc) {
        float p0 = exp2_fast(s[sc][0] - m);
        float p1 = exp2_fast(s[sc][1] - m);
        float p2 = exp2_fast(s[sc][2] - m);
        float p3 = exp2_fast(s[sc][3] - m);
        psum += (p0 + p1) + (p2 + p3);
        uint2 w;
        w.x = cvt_pk_bf16(p0, p1);
        w.y = cvt_pk_bf16(p2, p3);
        // logical byte (sc*32 + l4*8) in row, XOR-swizzled at 16B-slot level
        *(uint2*)(prow + ((sc * 32 + l4 * 8) ^ (swz << 4))) = w;
    }
    psum += __shfl_xor(psum, 16);
    psum += __shfl_xor(psum, 32);
    l += psum;

    asm volatile("s_waitcnt lgkmcnt(0)" ::: "memory");
    __builtin_amdgcn_sched_barrier(0);
    #pragma unroll
    for (int kc = 0; kc < 2; ++kc) {
        short8 pf = *(const short8*)(prow + ((kc * 64 + l4 * 16) ^ (swz << 4)));
        #pragma unroll
        for (int ec = 0; ec < 4; ++ec) {
            int vrow = ec * 16 + l16;
            int chunk = kc * 4 + l4;
            short8 vf = *(const short8*)&Vsb[vrow * 64 + ((chunk ^ swz) * 8)];
            o[ec] = MFMA16(pf, vf, o[ec]);
        }
    }
}

__global__ __launch_bounds__(256) void attn2(
        const unsigned short* __restrict__ qb, const unsigned short* __restrict__ kb,
        const unsigned short* __restrict__ vT, unsigned short* __restrict__ Ob) {
    __shared__ unsigned short Ks[2][64 * 64];
    __shared__ unsigned short Vs[2][64 * 64];
    __shared__ unsigned short Pl[4][16 * 64];

    const int blk = blockIdx.x;                 // 0..1023
    const int bh = (blk & 7) + 8 * ((blk >> 3) & 7);   // XCD-local bh
    const int pair = blk >> 6;                  // 0..15
    const int iA = pair, iB = 31 - pair;
    const int t0A = iA * 64, t0B = iB * 64;
    const int b = bh >> 4, h = bh & (H_ - 1);

    const int lane = threadIdx.x & 63, wid = threadIdx.x >> 6;
    const int l16 = lane & 15, l4 = lane >> 4;

    const unsigned short* kbase = kb + (size_t)bh * T_ * HD_;
    const unsigned short* vbase = vT + (size_t)bh * HD_ * T_;
    const unsigned short* qbase = qb + (size_t)bh * T_ * HD_;

    short8 qA0, qA1, qB0, qB1;
    {
        const unsigned short* qr = qbase + (size_t)(t0A + wid * 16 + l16) * HD_;
        qA0 = *(const short8*)(qr + l4 * 8);
        qA1 = *(const short8*)(qr + 32 + l4 * 8);
        qr = qbase + (size_t)(t0B + wid * 16 + l16) * HD_;
        qB0 = *(const short8*)(qr + l4 * 8);
        qB1 = *(const short8*)(qr + 32 + l4 * 8);
    }

    f32x4 oA[4] = {}, oB[4] = {};
    float mA = -__builtin_inff(), lA = 0.f;
    float mB = -__builtin_inff(), lB = 0.f;

    stage_kv(kbase, vbase, Ks[0], Vs[0], 0, wid, lane);
    asm volatile("s_waitcnt vmcnt(0)" ::: "memory");
    __syncthreads();

    for (int it = 0; it <= iB; ++it) {
        const int cur = it & 1;
        if (it < iB)
            stage_kv(kbase, vbase, Ks[cur ^ 1], Vs[cur ^ 1], (it + 1) * 64, wid, lane);
        if (it <= iA)
            attn_tile_step(Ks[cur], Vs[cur], Pl[wid], qA0, qA1, it == iA,
                           wid, l16, l4, oA, mA, lA);
        attn_tile_step(Ks[cur], Vs[cur], Pl[wid], qB0, qB1, it == iB,
                       wid, l16, l4, oB, mB, lB);
        asm volatile("s_waitcnt vmcnt(0)" ::: "memory");
        __syncthreads();
    }

    #pragma unroll
    for (int r = 0; r < 4; ++r) {
        float lr = __shfl(lA, l4 * 4 + r);
        float inv = 1.f / lr;
        int t = t0A + wid * 16 + l4 * 4 + r;
        unsigned short* orow = Ob + ((size_t)(b * T_ + t)) * D_ + h * HD_;
        #pragma unroll
        for (int ec = 0; ec < 4; ++ec)
            orow[ec * 16 + l16] = f2bf(oA[ec][r] * inv);
    }
    #pragma unroll
    for (int r = 0; r < 4; ++r) {
        float lr = __shfl(lB, l4 * 4 + r);
        float inv = 1.f / lr;
        int t = t0B + wid * 16 + l4 * 4 + r;
        unsigned short* orow = Ob + ((size_t)(b * T_ + t)) * D_ + h * HD_;
        #pragma unroll
        for (int ec = 0; ec < 4; ++ec)
            orow[ec * 16 + l16] = f2bf(oB[ec][r] * inv);
    }
}

// ---------------------------------------------------------------------------
// Output projection (unchanged)
// ---------------------------------------------------------------------------
__global__ __launch_bounds__(256) void proj_mfma(
        const unsigned short* __restrict__ A,
        const unsigned short* __restrict__ Bt,
        const float* __restrict__ bp, float* __restrict__ out) {
    __shared__ unsigned short As[128 * 32];
    __shared__ unsigned short Bs[128 * 32];
    const int tid = threadIdx.x;
    const int lane = tid & 63, wid = tid >> 6;
    const int l16 = lane & 15, l4 = lane >> 4;
    const int wr = wid >> 1, wc = wid & 1;
    const size_t m0 = blockIdx.y * 128, n0 = blockIdx.x * 128;

    f32x4 acc[4][4] = {};
    for (int k0 = 0; k0 < D_; k0 += 32) {
        #pragma unroll
        for (int c = 0; c < 2; ++c) {
            int idx = c * 256 + tid;
            int row = idx >> 2, q = idx & 3;
            gl_lds16(A  + (m0 + row) * (size_t)D_ + k0 + q * 8, &As[row * 32 + q * 8]);
            gl_lds16(Bt + (n0 + row) * (size_t)D_ + k0 + q * 8, &Bs[row * 32 + q * 8]);
        }
        __syncthreads();
        short8 a[4], b[4];
        #pragma unroll
        for (int i = 0; i < 4; ++i)
            a[i] = *(const short8*)&As[(wr * 64 + i * 16 + l16) * 32 + l4 * 8];
        #pragma unroll
        for (int j = 0; j < 4; ++j)
            b[j] = *(const short8*)&Bs[(wc * 64 + j * 16 + l16) * 32 + l4 * 8];
        #pragma unroll
        for (int i = 0; i < 4; ++i)
            #pragma unroll
            for (int j = 0; j < 4; ++j)
                acc[i][j] = MFMA16(a[i], b[j], acc[i][j]);
        __syncthreads();
    }

    #pragma unroll
    for (int j = 0; j < 4; ++j) {
        int n = (int)n0 + wc * 64 + j * 16 + l16;
        float bias = bp[n];
        #pragma unroll
        for (int i = 0; i < 4; ++i)
            #pragma unroll
            for (int r = 0; r < 4; ++r) {
                int m = (int)m0 + wr * 64 + i * 16 + l4 * 4 + r;
                out[(size_t)m * D_ + n] = acc[i][j][r] + bias;
            }
    }
}

// ---------------------------------------------------------------------------
extern "C" void kernel_launch(void* const* d_in, const int* in_sizes, int n_in,
                              void* d_out, int out_size, void* d_ws, size_t ws_size,
                              hipStream_t stream) {
    const float* x  = (const float*)d_in[0];
    const float* Wq = (const float*)d_in[1];
    const float* Wk = (const float*)d_in[2];
    const float* Wv = (const float*)d_in[3];
    const float* Wp = (const float*)d_in[4];
    const float* bp = (const float*)d_in[5];
    float* out = (float*)d_out;

    char* w = (char*)d_ws;
    unsigned short* xb  = (unsigned short*)w; w += (size_t)M_ * D_ * 2;
    unsigned short* Wt  = (unsigned short*)w; w += (size_t)3 * D_ * D_ * 2;
    unsigned short* Wpt = (unsigned short*)w; w += (size_t)D_ * D_ * 2;
    unsigned short* qb  = (unsigned short*)w; w += (size_t)BH_ * T_ * HD_ * 2;
    unsigned short* kb  = (unsigned short*)w; w += (size_t)BH_ * T_ * HD_ * 2;
    unsigned short* vT  = (unsigned short*)w; w += (size_t)BH_ * T_ * HD_ * 2;
    unsigned short* Ob  = (unsigned short*)w; w += (size_t)M_ * D_ * 2;

    cvt_x<<<dim3((M_ * D_ / 4 + 255) / 256), 256, 0, stream>>>(x, xb, M_ * D_ / 4);
    tcvt_qkv<<<dim3(16, 1, 48), 256, 0, stream>>>(Wq, Wk, Wv, Wt);
    tcvt<<<dim3(16, 16, 1), 256, 0, stream>>>(Wp, Wpt, D_, 0, 0, D_);

    qkv_mfma<<<dim3(24, 64), 256, 0, stream>>>(xb, Wt, qb, kb, vT);
    attn2<<<dim3(1024), 256, 0, stream>>>(qb, kb, vT, Ob);
    proj_mfma<<<dim3(8, 64), 256, 0, stream>>>(Ob, Wpt, bp, out);
}

// Round 5
// 207.920 us; speedup vs baseline: 10.3372x; 1.1031x over previous
//
#include <hip/hip_runtime.h>
#include <hip/hip_bf16.h>

#define B_  4
#define T_  2048
#define D_  1024
#define H_  16
#define HD_ 64
#define M_  (B_ * T_)          // 8192 rows
#define BH_ (B_ * H_)          // 64

typedef __attribute__((ext_vector_type(8))) short   short8;   // 8 x bf16 (4 VGPR)
typedef __attribute__((ext_vector_type(4))) float   f32x4;
typedef __attribute__((ext_vector_type(4))) unsigned short us4v;

#define MFMA16(a, b, c) __builtin_amdgcn_mfma_f32_16x16x32_bf16((a), (b), (c), 0, 0, 0)

__device__ __forceinline__ unsigned short f2bf(float f) {
    union { float f; unsigned u; } v; v.f = f;
    unsigned r = v.u + 0x7fffu + ((v.u >> 16) & 1u);   // round-nearest-even
    return (unsigned short)(r >> 16);
}

__device__ __forceinline__ float exp2_fast(float x) {
    float r; asm("v_exp_f32 %0, %1" : "=v"(r) : "v"(x)); return r;
}
__device__ __forceinline__ unsigned cvt_pk_bf16(float lo, float hi) {
    unsigned r; asm("v_cvt_pk_bf16_f32 %0, %1, %2" : "=v"(r) : "v"(lo), "v"(hi)); return r;
}

__device__ __forceinline__ void gl_lds16(const void* g, void* l) {
    __builtin_amdgcn_global_load_lds(
        (const __attribute__((address_space(1))) void*)g,
        (__attribute__((address_space(3))) void*)l, 16, 0, 0);
}

// ---------------------------------------------------------------------------
__global__ __launch_bounds__(256) void cvt_x(const float* __restrict__ x,
                                             unsigned short* __restrict__ xb, int n4) {
    int i = blockIdx.x * 256 + threadIdx.x;
    if (i < n4) {
        float4 v = ((const float4*)x)[i];
        us4v o;
        o[0] = f2bf(v.x); o[1] = f2bf(v.y); o[2] = f2bf(v.z); o[3] = f2bf(v.w);
        ((us4v*)xb)[i] = o;
    }
}

// ---------------------------------------------------------------------------
__global__ __launch_bounds__(256) void tcvt_qkv(
        const float* __restrict__ Wq, const float* __restrict__ Wk,
        const float* __restrict__ Wv, unsigned short* __restrict__ dst) {
    __shared__ float tile[64][65];
    int z = blockIdx.z;
    int sel = z >> 4, head = z & 15;
    const float* s = (sel == 0 ? Wq : (sel == 1 ? Wk : Wv)) + (size_t)head * D_ * HD_;
    int r0 = blockIdx.x * 64;               // k-range
    int tid = threadIdx.x;
    #pragma unroll
    for (int i = 0; i < 4; ++i) {
        int idx4 = i * 256 + tid;
        int r = idx4 >> 4, c4 = (idx4 & 15) * 4;
        float4 v = *(const float4*)&s[(size_t)(r0 + r) * HD_ + c4];
        tile[r][c4 + 0] = v.x; tile[r][c4 + 1] = v.y;
        tile[r][c4 + 2] = v.z; tile[r][c4 + 3] = v.w;
    }
    __syncthreads();
    #pragma unroll
    for (int i = 0; i < 4; ++i) {
        int idx4 = i * 256 + tid;
        int c = idx4 >> 4, r4 = (idx4 & 15) * 4;
        us4v o;
        o[0] = f2bf(tile[r4 + 0][c]); o[1] = f2bf(tile[r4 + 1][c]);
        o[2] = f2bf(tile[r4 + 2][c]); o[3] = f2bf(tile[r4 + 3][c]);
        *(us4v*)&dst[(size_t)(sel * 1024 + head * 64 + c) * D_ + r0 + r4] = o;
    }
}

// ---------------------------------------------------------------------------
__global__ __launch_bounds__(256) void tcvt(const float* __restrict__ src,
                                            unsigned short* __restrict__ dst,
                                            int src_ld, long src_z_str,
                                            int dst_row_base, int dst_ld) {
    __shared__ float tile[64][65];
    const float* s = src + (size_t)blockIdx.z * src_z_str;
    int r0 = blockIdx.x * 64, c0 = blockIdx.y * 64;
    int tid = threadIdx.x;
    #pragma unroll
    for (int i = 0; i < 4; ++i) {
        int idx4 = i * 256 + tid;
        int r = idx4 >> 4, c4 = (idx4 & 15) * 4;
        float4 v = *(const float4*)&s[(size_t)(r0 + r) * src_ld + c0 + c4];
        tile[r][c4 + 0] = v.x; tile[r][c4 + 1] = v.y;
        tile[r][c4 + 2] = v.z; tile[r][c4 + 3] = v.w;
    }
    __syncthreads();
    #pragma unroll
    for (int i = 0; i < 4; ++i) {
        int idx4 = i * 256 + tid;
        int c = idx4 >> 4, r4 = (idx4 & 15) * 4;
        us4v o;
        o[0] = f2bf(tile[r4 + 0][c]); o[1] = f2bf(tile[r4 + 1][c]);
        o[2] = f2bf(tile[r4 + 2][c]); o[3] = f2bf(tile[r4 + 3][c]);
        *(us4v*)&dst[(size_t)(dst_row_base + blockIdx.z * 64 + c0 + c) * dst_ld + r0 + r4] = o;
    }
}

// ---------------------------------------------------------------------------
// 2-phase double-buffered staging for the 128x128 GEMMs.
// Global source chunk pre-swizzled: q_log = q_phys ^ ((row>>1)&3); LDS dest
// linear (global_load_lds constraint); fragment reads apply the same XOR.
// ---------------------------------------------------------------------------
__device__ __forceinline__ void stage_ab(const unsigned short* __restrict__ A,
                                         const unsigned short* __restrict__ Bt,
                                         size_t m0, size_t n0, int k0,
                                         unsigned short* Asb, unsigned short* Bsb,
                                         int tid) {
    #pragma unroll
    for (int c = 0; c < 2; ++c) {
        int idx = c * 256 + tid;            // 0..511 = (row 0..127) x (chunk 0..3)
        int row = idx >> 2, qp = idx & 3;
        int ql = qp ^ ((row >> 1) & 3);     // pre-swizzled source chunk
        gl_lds16(A  + (m0 + row) * (size_t)D_ + k0 + ql * 8, Asb + idx * 8);
        gl_lds16(Bt + (n0 + row) * (size_t)D_ + k0 + ql * 8, Bsb + idx * 8);
    }
}

// ---------------------------------------------------------------------------
// QKV GEMM v2: 2-phase dbuf + swizzled LDS + XCD-chunked grid.
// q scaled by 0.125*log2(e) (attention softmax runs in exp2 domain).
// ---------------------------------------------------------------------------
__global__ __launch_bounds__(256) void qkv_mfma(
        const unsigned short* __restrict__ A,
        const unsigned short* __restrict__ Bt,
        unsigned short* __restrict__ qb, unsigned short* __restrict__ kb,
        unsigned short* __restrict__ vT) {
    __shared__ unsigned short As[2][128 * 32];
    __shared__ unsigned short Bs[2][128 * 32];
    const int tid = threadIdx.x;
    const int lane = tid & 63, wid = tid >> 6;
    const int l16 = lane & 15, l4 = lane >> 4;
    const int wr = wid >> 1, wc = wid & 1;
    const int ksw = (l16 >> 1) & 3;         // read-side swizzle

    // XCD-chunked mapping: each XCD owns 8 contiguous m-tiles x all 24 n-tiles
    const int orig = blockIdx.x;            // 1536 blocks, 1536%8==0 -> bijective
    const int wgid = (orig & 7) * 192 + (orig >> 3);
    const size_t m0 = (size_t)(wgid / 24) * 128;
    const size_t n0 = (size_t)(wgid % 24) * 128;

    f32x4 acc[4][4] = {};
    stage_ab(A, Bt, m0, n0, 0, As[0], Bs[0], tid);
    asm volatile("s_waitcnt vmcnt(0)" ::: "memory");
    __syncthreads();

    for (int t = 0; t < 32; ++t) {
        const int cur = t & 1;
        if (t < 31)
            stage_ab(A, Bt, m0, n0, (t + 1) * 32, As[cur ^ 1], Bs[cur ^ 1], tid);
        const unsigned short* Ab = As[cur];
        const unsigned short* Bb = Bs[cur];
        short8 a[4], b[4];
        #pragma unroll
        for (int i = 0; i < 4; ++i)
            a[i] = *(const short8*)&Ab[(wr * 64 + i * 16 + l16) * 32 + ((l4 ^ ksw) * 8)];
        #pragma unroll
        for (int j = 0; j < 4; ++j)
            b[j] = *(const short8*)&Bb[(wc * 64 + j * 16 + l16) * 32 + ((l4 ^ ksw) * 8)];
        #pragma unroll
        for (int i = 0; i < 4; ++i)
            #pragma unroll
            for (int j = 0; j < 4; ++j)
                acc[i][j] = MFMA16(a[i], b[j], acc[i][j]);
        asm volatile("s_waitcnt vmcnt(0)" ::: "memory");
        __syncthreads();
    }

    #pragma unroll
    for (int j = 0; j < 4; ++j) {
        int n = (int)n0 + wc * 64 + j * 16 + l16;
        int sel = n >> 10, h = (n >> 6) & (H_ - 1), e = n & 63;
        if (sel == 2) {
            #pragma unroll
            for (int i = 0; i < 4; ++i) {
                int m = (int)m0 + wr * 64 + i * 16 + l4 * 4;
                int b_ = m >> 11, tt = m & (T_ - 1);
                us4v o;
                #pragma unroll
                for (int r = 0; r < 4; ++r) o[r] = f2bf(acc[i][j][r]);
                *(us4v*)&vT[((size_t)(b_ * H_ + h) * HD_ + e) * T_ + tt] = o;
            }
        } else {
            float scale = (sel == 0) ? 0.18033688011112042f : 1.0f;  // 0.125*log2e
            unsigned short* dst = (sel == 0) ? qb : kb;
            #pragma unroll
            for (int i = 0; i < 4; ++i) {
                #pragma unroll
                for (int r = 0; r < 4; ++r) {
                    int m = (int)m0 + wr * 64 + i * 16 + l4 * 4 + r;
                    int b_ = m >> 11, tt = m & (T_ - 1);
                    dst[((size_t)(b_ * H_ + h) * T_ + tt) * HD_ + e] = f2bf(acc[i][j][r] * scale);
                }
            }
        }
    }
}

// ---------------------------------------------------------------------------
// Attention v4 (unchanged from round 4)
// ---------------------------------------------------------------------------
__device__ __forceinline__ void stage_kv(const unsigned short* kbase,
                                         const unsigned short* vbase,
                                         unsigned short* KsBuf, unsigned short* VsBuf,
                                         int jt, int wid, int lane) {
    int s = lane & 7, rl = lane >> 3;          // slot 0..7, row-in-chunk 0..7
    int cchunk = s ^ rl;                       // pre-swizzled source col-chunk
    #pragma unroll
    for (int cc = 0; cc < 2; ++cc) {
        int chunk = cc * 4 + wid;
        int r = chunk * 8 + rl;                // tile row 0..63
        gl_lds16(kbase + (size_t)(jt + r) * HD_ + cchunk * 8,
                 KsBuf + chunk * 512 + lane * 8);
        gl_lds16(vbase + (size_t)r * T_ + jt + cchunk * 8,
                 VsBuf + chunk * 512 + lane * 8);
    }
}

__device__ __forceinline__ void attn_tile_step(
        const unsigned short* Ksb, const unsigned short* Vsb, unsigned short* Pw,
        short8 qf0, short8 qf1, int diag, int wid, int l16, int l4,
        f32x4 (&o)[4], float& m, float& l) {
    f32x4 s[4];
    const int swz = l16 & 7;
    #pragma unroll
    for (int sc = 0; sc < 4; ++sc) {
        int row = sc * 16 + l16;
        int sl0 = l4 ^ swz;
        short8 kf0 = *(const short8*)&Ksb[row * 64 + sl0 * 8];
        short8 kf1 = *(const short8*)&Ksb[row * 64 + (sl0 ^ 4) * 8];
        f32x4 z = {0.f, 0.f, 0.f, 0.f};
        z = MFMA16(kf0, qf0, z);            // swapped: S^T[key][query]
        z = MFMA16(kf1, qf1, z);
        s[sc] = z;
    }
    if (diag) {
        int qloc = wid * 16 + l16;
        #pragma unroll
        for (int sc = 0; sc < 4; ++sc) {
            int kb0 = sc * 16 + l4 * 4;
            #pragma unroll
            for (int r = 0; r < 4; ++r)
                if (kb0 + r > qloc) s[sc][r] = -1e30f;
        }
    }
    // this thread holds 16 keys of query l16
    float vmax = s[0][0];
    #pragma unroll
    for (int sc = 0; sc < 4; ++sc)
        #pragma unroll
        for (int r = 0; r < 4; ++r) vmax = fmaxf(vmax, s[sc][r]);
    vmax = fmaxf(vmax, __shfl_xor(vmax, 16));
    vmax = fmaxf(vmax, __shfl_xor(vmax, 32));

    if (!__all(vmax - m <= 8.0f)) {         // defer-max
        float mn = fmaxf(m, vmax);
        float corr = exp2_fast(m - mn);     // m=-inf -> 0
        m = mn;
        l *= corr;
        #pragma unroll
        for (int r = 0; r < 4; ++r) {
            float cr = __shfl(corr, l4 * 4 + r);
            #pragma unroll
            for (int ec = 0; ec < 4; ++ec) o[ec][r] *= cr;
        }
    }
    float psum = 0.f;
    char* prow = (char*)Pw + l16 * 128;
    #pragma unroll
    for (int sc = 0; sc < 4; ++sc) {
        float p0 = exp2_fast(s[sc][0] - m);
        float p1 = exp2_fast(s[sc][1] - m);
        float p2 = exp2_fast(s[sc][2] - m);
        float p3 = exp2_fast(s[sc][3] - m);
        psum += (p0 + p1) + (p2 + p3);
        uint2 w;
        w.x = cvt_pk_bf16(p0, p1);
        w.y = cvt_pk_bf16(p2, p3);
        *(uint2*)(prow + ((sc * 32 + l4 * 8) ^ (swz << 4))) = w;
    }
    psum += __shfl_xor(psum, 16);
    psum += __shfl_xor(psum, 32);
    l += psum;

    asm volatile("s_waitcnt lgkmcnt(0)" ::: "memory");
    __builtin_amdgcn_sched_barrier(0);
    #pragma unroll
    for (int kc = 0; kc < 2; ++kc) {
        short8 pf = *(const short8*)(prow + ((kc * 64 + l4 * 16) ^ (swz << 4)));
        #pragma unroll
        for (int ec = 0; ec < 4; ++ec) {
            int vrow = ec * 16 + l16;
            int chunk = kc * 4 + l4;
            short8 vf = *(const short8*)&Vsb[vrow * 64 + ((chunk ^ swz) * 8)];
            o[ec] = MFMA16(pf, vf, o[ec]);
        }
    }
}

__global__ __launch_bounds__(256) void attn2(
        const unsigned short* __restrict__ qb, const unsigned short* __restrict__ kb,
        const unsigned short* __restrict__ vT, unsigned short* __restrict__ Ob) {
    __shared__ unsigned short Ks[2][64 * 64];
    __shared__ unsigned short Vs[2][64 * 64];
    __shared__ unsigned short Pl[4][16 * 64];

    const int blk = blockIdx.x;                 // 0..1023
    const int bh = (blk & 7) + 8 * ((blk >> 3) & 7);   // XCD-local bh
    const int pair = blk >> 6;                  // 0..15
    const int iA = pair, iB = 31 - pair;
    const int t0A = iA * 64, t0B = iB * 64;
    const int b = bh >> 4, h = bh & (H_ - 1);

    const int lane = threadIdx.x & 63, wid = threadIdx.x >> 6;
    const int l16 = lane & 15, l4 = lane >> 4;

    const unsigned short* kbase = kb + (size_t)bh * T_ * HD_;
    const unsigned short* vbase = vT + (size_t)bh * HD_ * T_;
    const unsigned short* qbase = qb + (size_t)bh * T_ * HD_;

    short8 qA0, qA1, qB0, qB1;
    {
        const unsigned short* qr = qbase + (size_t)(t0A + wid * 16 + l16) * HD_;
        qA0 = *(const short8*)(qr + l4 * 8);
        qA1 = *(const short8*)(qr + 32 + l4 * 8);
        qr = qbase + (size_t)(t0B + wid * 16 + l16) * HD_;
        qB0 = *(const short8*)(qr + l4 * 8);
        qB1 = *(const short8*)(qr + 32 + l4 * 8);
    }

    f32x4 oA[4] = {}, oB[4] = {};
    float mA = -__builtin_inff(), lA = 0.f;
    float mB = -__builtin_inff(), lB = 0.f;

    stage_kv(kbase, vbase, Ks[0], Vs[0], 0, wid, lane);
    asm volatile("s_waitcnt vmcnt(0)" ::: "memory");
    __syncthreads();

    for (int it = 0; it <= iB; ++it) {
        const int cur = it & 1;
        if (it < iB)
            stage_kv(kbase, vbase, Ks[cur ^ 1], Vs[cur ^ 1], (it + 1) * 64, wid, lane);
        if (it <= iA)
            attn_tile_step(Ks[cur], Vs[cur], Pl[wid], qA0, qA1, it == iA,
                           wid, l16, l4, oA, mA, lA);
        attn_tile_step(Ks[cur], Vs[cur], Pl[wid], qB0, qB1, it == iB,
                       wid, l16, l4, oB, mB, lB);
        asm volatile("s_waitcnt vmcnt(0)" ::: "memory");
        __syncthreads();
    }

    #pragma unroll
    for (int r = 0; r < 4; ++r) {
        float lr = __shfl(lA, l4 * 4 + r);
        float inv = 1.f / lr;
        int t = t0A + wid * 16 + l4 * 4 + r;
        unsigned short* orow = Ob + ((size_t)(b * T_ + t)) * D_ + h * HD_;
        #pragma unroll
        for (int ec = 0; ec < 4; ++ec)
            orow[ec * 16 + l16] = f2bf(oA[ec][r] * inv);
    }
    #pragma unroll
    for (int r = 0; r < 4; ++r) {
        float lr = __shfl(lB, l4 * 4 + r);
        float inv = 1.f / lr;
        int t = t0B + wid * 16 + l4 * 4 + r;
        unsigned short* orow = Ob + ((size_t)(b * T_ + t)) * D_ + h * HD_;
        #pragma unroll
        for (int ec = 0; ec < 4; ++ec)
            orow[ec * 16 + l16] = f2bf(oB[ec][r] * inv);
    }
}

// ---------------------------------------------------------------------------
// Output projection v2: 2-phase dbuf + swizzled LDS + XCD-chunked grid.
// ---------------------------------------------------------------------------
__global__ __launch_bounds__(256) void proj_mfma(
        const unsigned short* __restrict__ A,
        const unsigned short* __restrict__ Bt,
        const float* __restrict__ bp, float* __restrict__ out) {
    __shared__ unsigned short As[2][128 * 32];
    __shared__ unsigned short Bs[2][128 * 32];
    const int tid = threadIdx.x;
    const int lane = tid & 63, wid = tid >> 6;
    const int l16 = lane & 15, l4 = lane >> 4;
    const int wr = wid >> 1, wc = wid & 1;
    const int ksw = (l16 >> 1) & 3;

    const int orig = blockIdx.x;            // 512 blocks, 512%8==0 -> bijective
    const int wgid = (orig & 7) * 64 + (orig >> 3);
    const size_t m0 = (size_t)(wgid >> 3) * 128;
    const size_t n0 = (size_t)(wgid & 7) * 128;

    f32x4 acc[4][4] = {};
    stage_ab(A, Bt, m0, n0, 0, As[0], Bs[0], tid);
    asm volatile("s_waitcnt vmcnt(0)" ::: "memory");
    __syncthreads();

    for (int t = 0; t < 32; ++t) {
        const int cur = t & 1;
        if (t < 31)
            stage_ab(A, Bt, m0, n0, (t + 1) * 32, As[cur ^ 1], Bs[cur ^ 1], tid);
        const unsigned short* Ab = As[cur];
        const unsigned short* Bb = Bs[cur];
        short8 a[4], b[4];
        #pragma unroll
        for (int i = 0; i < 4; ++i)
            a[i] = *(const short8*)&Ab[(wr * 64 + i * 16 + l16) * 32 + ((l4 ^ ksw) * 8)];
        #pragma unroll
        for (int j = 0; j < 4; ++j)
            b[j] = *(const short8*)&Bb[(wc * 64 + j * 16 + l16) * 32 + ((l4 ^ ksw) * 8)];
        #pragma unroll
        for (int i = 0; i < 4; ++i)
            #pragma unroll
            for (int j = 0; j < 4; ++j)
                acc[i][j] = MFMA16(a[i], b[j], acc[i][j]);
        asm volatile("s_waitcnt vmcnt(0)" ::: "memory");
        __syncthreads();
    }

    #pragma unroll
    for (int j = 0; j < 4; ++j) {
        int n = (int)n0 + wc * 64 + j * 16 + l16;
        float bias = bp[n];
        #pragma unroll
        for (int i = 0; i < 4; ++i)
            #pragma unroll
            for (int r = 0; r < 4; ++r) {
                int m = (int)m0 + wr * 64 + i * 16 + l4 * 4 + r;
                out[(size_t)m * D_ + n] = acc[i][j][r] + bias;
            }
    }
}

// ---------------------------------------------------------------------------
extern "C" void kernel_launch(void* const* d_in, const int* in_sizes, int n_in,
                              void* d_out, int out_size, void* d_ws, size_t ws_size,
                              hipStream_t stream) {
    const float* x  = (const float*)d_in[0];
    const float* Wq = (const float*)d_in[1];
    const float* Wk = (const float*)d_in[2];
    const float* Wv = (const float*)d_in[3];
    const float* Wp = (const float*)d_in[4];
    const float* bp = (const float*)d_in[5];
    float* out = (float*)d_out;

    char* w = (char*)d_ws;
    unsigned short* xb  = (unsigned short*)w; w += (size_t)M_ * D_ * 2;
    unsigned short* Wt  = (unsigned short*)w; w += (size_t)3 * D_ * D_ * 2;
    unsigned short* Wpt = (unsigned short*)w; w += (size_t)D_ * D_ * 2;
    unsigned short* qb  = (unsigned short*)w; w += (size_t)BH_ * T_ * HD_ * 2;
    unsigned short* kb  = (unsigned short*)w; w += (size_t)BH_ * T_ * HD_ * 2;
    unsigned short* vT  = (unsigned short*)w; w += (size_t)BH_ * T_ * HD_ * 2;
    unsigned short* Ob  = (unsigned short*)w; w += (size_t)M_ * D_ * 2;

    cvt_x<<<dim3((M_ * D_ / 4 + 255) / 256), 256, 0, stream>>>(x, xb, M_ * D_ / 4);
    tcvt_qkv<<<dim3(16, 1, 48), 256, 0, stream>>>(Wq, Wk, Wv, Wt);
    tcvt<<<dim3(16, 16, 1), 256, 0, stream>>>(Wp, Wpt, D_, 0, 0, D_);

    qkv_mfma<<<dim3(1536), 256, 0, stream>>>(xb, Wt, qb, kb, vT);
    attn2<<<dim3(1024), 256, 0, stream>>>(qb, kb, vT, Ob);
    proj_mfma<<<dim3(512), 256, 0, stream>>>(Ob, Wpt, bp, out);
}

// Round 6
// 204.309 us; speedup vs baseline: 10.5199x; 1.0177x over previous
//
#include <hip/hip_runtime.h>
#include <hip/hip_bf16.h>

#define B_  4
#define T_  2048
#define D_  1024
#define H_  16
#define HD_ 64
#define M_  (B_ * T_)          // 8192 rows
#define BH_ (B_ * H_)          // 64

typedef __attribute__((ext_vector_type(8))) short   short8;   // 8 x bf16 (4 VGPR)
typedef __attribute__((ext_vector_type(4))) float   f32x4;
typedef __attribute__((ext_vector_type(4))) unsigned short us4v;

#define MFMA16(a, b, c) __builtin_amdgcn_mfma_f32_16x16x32_bf16((a), (b), (c), 0, 0, 0)

__device__ __forceinline__ unsigned short f2bf(float f) {
    union { float f; unsigned u; } v; v.f = f;
    unsigned r = v.u + 0x7fffu + ((v.u >> 16) & 1u);   // round-nearest-even
    return (unsigned short)(r >> 16);
}

__device__ __forceinline__ float exp2_fast(float x) {
    float r; asm("v_exp_f32 %0, %1" : "=v"(r) : "v"(x)); return r;
}
__device__ __forceinline__ unsigned cvt_pk_bf16(float lo, float hi) {
    unsigned r; asm("v_cvt_pk_bf16_f32 %0, %1, %2" : "=v"(r) : "v"(lo), "v"(hi)); return r;
}
__device__ __forceinline__ int bperm(int addr, int src) {
    return __builtin_amdgcn_ds_bpermute(addr, src);
}

__device__ __forceinline__ void gl_lds16(const void* g, void* l) {
    __builtin_amdgcn_global_load_lds(
        (const __attribute__((address_space(1))) void*)g,
        (__attribute__((address_space(3))) void*)l, 16, 0, 0);
}

// ---------------------------------------------------------------------------
__global__ __launch_bounds__(256) void cvt_x(const float* __restrict__ x,
                                             unsigned short* __restrict__ xb, int n4) {
    int i = blockIdx.x * 256 + threadIdx.x;
    if (i < n4) {
        float4 v = ((const float4*)x)[i];
        us4v o;
        o[0] = f2bf(v.x); o[1] = f2bf(v.y); o[2] = f2bf(v.z); o[3] = f2bf(v.w);
        ((us4v*)xb)[i] = o;
    }
}

// ---------------------------------------------------------------------------
__global__ __launch_bounds__(256) void tcvt_qkv(
        const float* __restrict__ Wq, const float* __restrict__ Wk,
        const float* __restrict__ Wv, unsigned short* __restrict__ dst) {
    __shared__ float tile[64][65];
    int z = blockIdx.z;
    int sel = z >> 4, head = z & 15;
    const float* s = (sel == 0 ? Wq : (sel == 1 ? Wk : Wv)) + (size_t)head * D_ * HD_;
    int r0 = blockIdx.x * 64;               // k-range
    int tid = threadIdx.x;
    #pragma unroll
    for (int i = 0; i < 4; ++i) {
        int idx4 = i * 256 + tid;
        int r = idx4 >> 4, c4 = (idx4 & 15) * 4;
        float4 v = *(const float4*)&s[(size_t)(r0 + r) * HD_ + c4];
        tile[r][c4 + 0] = v.x; tile[r][c4 + 1] = v.y;
        tile[r][c4 + 2] = v.z; tile[r][c4 + 3] = v.w;
    }
    __syncthreads();
    #pragma unroll
    for (int i = 0; i < 4; ++i) {
        int idx4 = i * 256 + tid;
        int c = idx4 >> 4, r4 = (idx4 & 15) * 4;
        us4v o;
        o[0] = f2bf(tile[r4 + 0][c]); o[1] = f2bf(tile[r4 + 1][c]);
        o[2] = f2bf(tile[r4 + 2][c]); o[3] = f2bf(tile[r4 + 3][c]);
        *(us4v*)&dst[(size_t)(sel * 1024 + head * 64 + c) * D_ + r0 + r4] = o;
    }
}

// ---------------------------------------------------------------------------
__global__ __launch_bounds__(256) void tcvt(const float* __restrict__ src,
                                            unsigned short* __restrict__ dst,
                                            int src_ld, long src_z_str,
                                            int dst_row_base, int dst_ld) {
    __shared__ float tile[64][65];
    const float* s = src + (size_t)blockIdx.z * src_z_str;
    int r0 = blockIdx.x * 64, c0 = blockIdx.y * 64;
    int tid = threadIdx.x;
    #pragma unroll
    for (int i = 0; i < 4; ++i) {
        int idx4 = i * 256 + tid;
        int r = idx4 >> 4, c4 = (idx4 & 15) * 4;
        float4 v = *(const float4*)&s[(size_t)(r0 + r) * src_ld + c0 + c4];
        tile[r][c4 + 0] = v.x; tile[r][c4 + 1] = v.y;
        tile[r][c4 + 2] = v.z; tile[r][c4 + 3] = v.w;
    }
    __syncthreads();
    #pragma unroll
    for (int i = 0; i < 4; ++i) {
        int idx4 = i * 256 + tid;
        int c = idx4 >> 4, r4 = (idx4 & 15) * 4;
        us4v o;
        o[0] = f2bf(tile[r4 + 0][c]); o[1] = f2bf(tile[r4 + 1][c]);
        o[2] = f2bf(tile[r4 + 2][c]); o[3] = f2bf(tile[r4 + 3][c]);
        *(us4v*)&dst[(size_t)(dst_row_base + blockIdx.z * 64 + c0 + c) * dst_ld + r0 + r4] = o;
    }
}

// ---------------------------------------------------------------------------
// 2-phase double-buffered staging for the 128x128 GEMMs (unchanged).
// ---------------------------------------------------------------------------
__device__ __forceinline__ void stage_ab(const unsigned short* __restrict__ A,
                                         const unsigned short* __restrict__ Bt,
                                         size_t m0, size_t n0, int k0,
                                         unsigned short* Asb, unsigned short* Bsb,
                                         int tid) {
    #pragma unroll
    for (int c = 0; c < 2; ++c) {
        int idx = c * 256 + tid;            // 0..511 = (row 0..127) x (chunk 0..3)
        int row = idx >> 2, qp = idx & 3;
        int ql = qp ^ ((row >> 1) & 3);     // pre-swizzled source chunk
        gl_lds16(A  + (m0 + row) * (size_t)D_ + k0 + ql * 8, Asb + idx * 8);
        gl_lds16(Bt + (n0 + row) * (size_t)D_ + k0 + ql * 8, Bsb + idx * 8);
    }
}

// ---------------------------------------------------------------------------
// QKV GEMM v2 (unchanged from round 5)
// ---------------------------------------------------------------------------
__global__ __launch_bounds__(256) void qkv_mfma(
        const unsigned short* __restrict__ A,
        const unsigned short* __restrict__ Bt,
        unsigned short* __restrict__ qb, unsigned short* __restrict__ kb,
        unsigned short* __restrict__ vT) {
    __shared__ unsigned short As[2][128 * 32];
    __shared__ unsigned short Bs[2][128 * 32];
    const int tid = threadIdx.x;
    const int lane = tid & 63, wid = tid >> 6;
    const int l16 = lane & 15, l4 = lane >> 4;
    const int wr = wid >> 1, wc = wid & 1;
    const int ksw = (l16 >> 1) & 3;         // read-side swizzle

    const int orig = blockIdx.x;            // 1536 blocks, 1536%8==0 -> bijective
    const int wgid = (orig & 7) * 192 + (orig >> 3);
    const size_t m0 = (size_t)(wgid / 24) * 128;
    const size_t n0 = (size_t)(wgid % 24) * 128;

    f32x4 acc[4][4] = {};
    stage_ab(A, Bt, m0, n0, 0, As[0], Bs[0], tid);
    asm volatile("s_waitcnt vmcnt(0)" ::: "memory");
    __syncthreads();

    for (int t = 0; t < 32; ++t) {
        const int cur = t & 1;
        if (t < 31)
            stage_ab(A, Bt, m0, n0, (t + 1) * 32, As[cur ^ 1], Bs[cur ^ 1], tid);
        const unsigned short* Ab = As[cur];
        const unsigned short* Bb = Bs[cur];
        short8 a[4], b[4];
        #pragma unroll
        for (int i = 0; i < 4; ++i)
            a[i] = *(const short8*)&Ab[(wr * 64 + i * 16 + l16) * 32 + ((l4 ^ ksw) * 8)];
        #pragma unroll
        for (int j = 0; j < 4; ++j)
            b[j] = *(const short8*)&Bb[(wc * 64 + j * 16 + l16) * 32 + ((l4 ^ ksw) * 8)];
        #pragma unroll
        for (int i = 0; i < 4; ++i)
            #pragma unroll
            for (int j = 0; j < 4; ++j)
                acc[i][j] = MFMA16(a[i], b[j], acc[i][j]);
        asm volatile("s_waitcnt vmcnt(0)" ::: "memory");
        __syncthreads();
    }

    #pragma unroll
    for (int j = 0; j < 4; ++j) {
        int n = (int)n0 + wc * 64 + j * 16 + l16;
        int sel = n >> 10, h = (n >> 6) & (H_ - 1), e = n & 63;
        if (sel == 2) {
            #pragma unroll
            for (int i = 0; i < 4; ++i) {
                int m = (int)m0 + wr * 64 + i * 16 + l4 * 4;
                int b_ = m >> 11, tt = m & (T_ - 1);
                us4v o;
                #pragma unroll
                for (int r = 0; r < 4; ++r) o[r] = f2bf(acc[i][j][r]);
                *(us4v*)&vT[((size_t)(b_ * H_ + h) * HD_ + e) * T_ + tt] = o;
            }
        } else {
            float scale = (sel == 0) ? 0.18033688011112042f : 1.0f;  // 0.125*log2e
            unsigned short* dst = (sel == 0) ? qb : kb;
            #pragma unroll
            for (int i = 0; i < 4; ++i) {
                #pragma unroll
                for (int r = 0; r < 4; ++r) {
                    int m = (int)m0 + wr * 64 + i * 16 + l4 * 4 + r;
                    int b_ = m >> 11, tt = m & (T_ - 1);
                    dst[((size_t)(b_ * H_ + h) * T_ + tt) * HD_ + e] = f2bf(acc[i][j][r] * scale);
                }
            }
        }
    }
}

// ---------------------------------------------------------------------------
// Attention v5: P relayout in-register via ds_bpermute (no P LDS, no lgkmcnt
// drain), A/B chains fully independent + interleaved, setprio around MFMA.
// ---------------------------------------------------------------------------
__device__ __forceinline__ void stage_kv(const unsigned short* kbase,
                                         const unsigned short* vbase,
                                         unsigned short* KsBuf, unsigned short* VsBuf,
                                         int jt, int wid, int lane) {
    int s = lane & 7, rl = lane >> 3;          // slot 0..7, row-in-chunk 0..7
    int cchunk = s ^ rl;                       // pre-swizzled source col-chunk
    #pragma unroll
    for (int cc = 0; cc < 2; ++cc) {
        int chunk = cc * 4 + wid;
        int r = chunk * 8 + rl;                // tile row 0..63
        gl_lds16(kbase + (size_t)(jt + r) * HD_ + cchunk * 8,
                 KsBuf + chunk * 512 + lane * 8);
        gl_lds16(vbase + (size_t)r * T_ + jt + cchunk * 8,
                 VsBuf + chunk * 512 + lane * 8);
    }
}

// S^T = K Q^T (8 MFMA), optional diagonal causal mask.
__device__ __forceinline__ void qk_score(const unsigned short* Ksb,
        short8 qf0, short8 qf1, int diag, int wid, int l16, int l4,
        f32x4 (&s)[4]) {
    const int swz = l16 & 7;
    __builtin_amdgcn_s_setprio(1);
    #pragma unroll
    for (int sc = 0; sc < 4; ++sc) {
        int row = sc * 16 + l16;
        int sl0 = l4 ^ swz;
        short8 kf0 = *(const short8*)&Ksb[row * 64 + sl0 * 8];
        short8 kf1 = *(const short8*)&Ksb[row * 64 + (sl0 ^ 4) * 8];
        f32x4 z = {0.f, 0.f, 0.f, 0.f};
        z = MFMA16(kf0, qf0, z);            // swapped: S^T[key][query]
        z = MFMA16(kf1, qf1, z);
        s[sc] = z;
    }
    __builtin_amdgcn_s_setprio(0);
    if (diag) {
        int qloc = wid * 16 + l16;
        #pragma unroll
        for (int sc = 0; sc < 4; ++sc) {
            int kb0 = sc * 16 + l4 * 4;
            #pragma unroll
            for (int r = 0; r < 4; ++r)
                if (kb0 + r > qloc) s[sc][r] = -1e30f;
        }
    }
}

// Online softmax (thread owns 16 keys of query l16); packs P to bf16 words
// W[s][c] = keys (16s + 4*l4 + 2c, +1).
__device__ __forceinline__ void sm_pack(const f32x4 (&s)[4],
        int l16, int l4, f32x4 (&o)[4], float& m, float& l,
        unsigned (&W)[4][2]) {
    float vmax = s[0][0];
    #pragma unroll
    for (int sc = 0; sc < 4; ++sc)
        #pragma unroll
        for (int r = 0; r < 4; ++r) vmax = fmaxf(vmax, s[sc][r]);
    vmax = fmaxf(vmax, __shfl_xor(vmax, 16));
    vmax = fmaxf(vmax, __shfl_xor(vmax, 32));

    if (!__all(vmax - m <= 8.0f)) {         // defer-max
        float mn = fmaxf(m, vmax);
        float corr = exp2_fast(m - mn);     // m=-inf -> 0
        m = mn;
        l *= corr;
        #pragma unroll
        for (int r = 0; r < 4; ++r) {
            float cr = __shfl(corr, l4 * 4 + r);
            #pragma unroll
            for (int ec = 0; ec < 4; ++ec) o[ec][r] *= cr;
        }
    }
    float psum = 0.f;
    #pragma unroll
    for (int sc = 0; sc < 4; ++sc) {
        float p0 = exp2_fast(s[sc][0] - m);
        float p1 = exp2_fast(s[sc][1] - m);
        float p2 = exp2_fast(s[sc][2] - m);
        float p3 = exp2_fast(s[sc][3] - m);
        psum += (p0 + p1) + (p2 + p3);
        W[sc][0] = cvt_pk_bf16(p0, p1);
        W[sc][1] = cvt_pk_bf16(p2, p3);
    }
    psum += __shfl_xor(psum, 16);
    psum += __shfl_xor(psum, 32);
    l += psum;
}

// O += P V. P A-fragment built in-register: target lane (a=l4,l16) word t
// pulls W[kc*2 + (a>>1)][t&1] from lane (2(a&1)+(t>>1))*16+l16.
__device__ __forceinline__ void pv_acc(const unsigned short* Vsb,
        const unsigned (&W)[4][2], int l16, int l4, int addrLo, bool sel_lo,
        f32x4 (&o)[4]) {
    const int swz = l16 & 7;
    const int addrHi = addrLo + 64;
    #pragma unroll
    for (int kc = 0; kc < 2; ++kc) {
        int b0, b1;
        union { unsigned u[4]; short8 s; } pu;
        b0 = bperm(addrLo, (int)W[kc * 2][0]);
        b1 = bperm(addrLo, (int)W[kc * 2 + 1][0]);
        pu.u[0] = sel_lo ? (unsigned)b0 : (unsigned)b1;
        b0 = bperm(addrLo, (int)W[kc * 2][1]);
        b1 = bperm(addrLo, (int)W[kc * 2 + 1][1]);
        pu.u[1] = sel_lo ? (unsigned)b0 : (unsigned)b1;
        b0 = bperm(addrHi, (int)W[kc * 2][0]);
        b1 = bperm(addrHi, (int)W[kc * 2 + 1][0]);
        pu.u[2] = sel_lo ? (unsigned)b0 : (unsigned)b1;
        b0 = bperm(addrHi, (int)W[kc * 2][1]);
        b1 = bperm(addrHi, (int)W[kc * 2 + 1][1]);
        pu.u[3] = sel_lo ? (unsigned)b0 : (unsigned)b1;
        short8 pf = pu.s;
        __builtin_amdgcn_s_setprio(1);
        #pragma unroll
        for (int ec = 0; ec < 4; ++ec) {
            int vrow = ec * 16 + l16;
            int chunk = kc * 4 + l4;
            short8 vf = *(const short8*)&Vsb[vrow * 64 + ((chunk ^ swz) * 8)];
            o[ec] = MFMA16(pf, vf, o[ec]);
        }
        __builtin_amdgcn_s_setprio(0);
    }
}

__global__ __launch_bounds__(256, 4) void attn2(
        const unsigned short* __restrict__ qb, const unsigned short* __restrict__ kb,
        const unsigned short* __restrict__ vT, unsigned short* __restrict__ Ob) {
    __shared__ unsigned short Ks[2][64 * 64];
    __shared__ unsigned short Vs[2][64 * 64];

    const int blk = blockIdx.x;                 // 0..1023
    const int bh = (blk & 7) + 8 * ((blk >> 3) & 7);   // XCD-local bh
    const int pair = blk >> 6;                  // 0..15
    const int iA = pair, iB = 31 - pair;
    const int t0A = iA * 64, t0B = iB * 64;
    const int b = bh >> 4, h = bh & (H_ - 1);

    const int lane = threadIdx.x & 63, wid = threadIdx.x >> 6;
    const int l16 = lane & 15, l4 = lane >> 4;
    const int addrLo = ((2 * (l4 & 1)) * 16 + l16) * 4;   // bpermute byte addr
    const bool sel_lo = (l4 < 2);

    const unsigned short* kbase = kb + (size_t)bh * T_ * HD_;
    const unsigned short* vbase = vT + (size_t)bh * HD_ * T_;
    const unsigned short* qbase = qb + (size_t)bh * T_ * HD_;

    short8 qA0, qA1, qB0, qB1;
    {
        const unsigned short* qr = qbase + (size_t)(t0A + wid * 16 + l16) * HD_;
        qA0 = *(const short8*)(qr + l4 * 8);
        qA1 = *(const short8*)(qr + 32 + l4 * 8);
        qr = qbase + (size_t)(t0B + wid * 16 + l16) * HD_;
        qB0 = *(const short8*)(qr + l4 * 8);
        qB1 = *(const short8*)(qr + 32 + l4 * 8);
    }

    f32x4 oA[4] = {}, oB[4] = {};
    float mA = -__builtin_inff(), lA = 0.f;
    float mB = -__builtin_inff(), lB = 0.f;

    stage_kv(kbase, vbase, Ks[0], Vs[0], 0, wid, lane);
    asm volatile("s_waitcnt vmcnt(0)" ::: "memory");
    __syncthreads();

    for (int it = 0; it <= iB; ++it) {
        const int cur = it & 1;
        if (it < iB)
            stage_kv(kbase, vbase, Ks[cur ^ 1], Vs[cur ^ 1], (it + 1) * 64, wid, lane);
        const unsigned short* Ksb = Ks[cur];
        const unsigned short* Vsb = Vs[cur];
        if (it <= iA) {
            // dual-chain iteration: interleave so B's MFMA hides A's VALU
            f32x4 sA[4];
            qk_score(Ksb, qA0, qA1, it == iA, wid, l16, l4, sA);
            unsigned WA[4][2];
            sm_pack(sA, l16, l4, oA, mA, lA, WA);
            f32x4 sB[4];
            qk_score(Ksb, qB0, qB1, 0, wid, l16, l4, sB);
            pv_acc(Vsb, WA, l16, l4, addrLo, sel_lo, oA);
            unsigned WB[4][2];
            sm_pack(sB, l16, l4, oB, mB, lB, WB);
            pv_acc(Vsb, WB, l16, l4, addrLo, sel_lo, oB);
        } else {
            f32x4 sB[4];
            qk_score(Ksb, qB0, qB1, it == iB, wid, l16, l4, sB);
            unsigned WB[4][2];
            sm_pack(sB, l16, l4, oB, mB, lB, WB);
            pv_acc(Vsb, WB, l16, l4, addrLo, sel_lo, oB);
        }
        asm volatile("s_waitcnt vmcnt(0)" ::: "memory");
        __syncthreads();
    }

    #pragma unroll
    for (int r = 0; r < 4; ++r) {
        float lr = __shfl(lA, l4 * 4 + r);
        float inv = 1.f / lr;
        int t = t0A + wid * 16 + l4 * 4 + r;
        unsigned short* orow = Ob + ((size_t)(b * T_ + t)) * D_ + h * HD_;
        #pragma unroll
        for (int ec = 0; ec < 4; ++ec)
            orow[ec * 16 + l16] = f2bf(oA[ec][r] * inv);
    }
    #pragma unroll
    for (int r = 0; r < 4; ++r) {
        float lr = __shfl(lB, l4 * 4 + r);
        float inv = 1.f / lr;
        int t = t0B + wid * 16 + l4 * 4 + r;
        unsigned short* orow = Ob + ((size_t)(b * T_ + t)) * D_ + h * HD_;
        #pragma unroll
        for (int ec = 0; ec < 4; ++ec)
            orow[ec * 16 + l16] = f2bf(oB[ec][r] * inv);
    }
}

// ---------------------------------------------------------------------------
// Output projection v2 (unchanged from round 5)
// ---------------------------------------------------------------------------
__global__ __launch_bounds__(256) void proj_mfma(
        const unsigned short* __restrict__ A,
        const unsigned short* __restrict__ Bt,
        const float* __restrict__ bp, float* __restrict__ out) {
    __shared__ unsigned short As[2][128 * 32];
    __shared__ unsigned short Bs[2][128 * 32];
    const int tid = threadIdx.x;
    const int lane = tid & 63, wid = tid >> 6;
    const int l16 = lane & 15, l4 = lane >> 4;
    const int wr = wid >> 1, wc = wid & 1;
    const int ksw = (l16 >> 1) & 3;

    const int orig = blockIdx.x;            // 512 blocks, 512%8==0 -> bijective
    const int wgid = (orig & 7) * 64 + (orig >> 3);
    const size_t m0 = (size_t)(wgid >> 3) * 128;
    const size_t n0 = (size_t)(wgid & 7) * 128;

    f32x4 acc[4][4] = {};
    stage_ab(A, Bt, m0, n0, 0, As[0], Bs[0], tid);
    asm volatile("s_waitcnt vmcnt(0)" ::: "memory");
    __syncthreads();

    for (int t = 0; t < 32; ++t) {
        const int cur = t & 1;
        if (t < 31)
            stage_ab(A, Bt, m0, n0, (t + 1) * 32, As[cur ^ 1], Bs[cur ^ 1], tid);
        const unsigned short* Ab = As[cur];
        const unsigned short* Bb = Bs[cur];
        short8 a[4], b[4];
        #pragma unroll
        for (int i = 0; i < 4; ++i)
            a[i] = *(const short8*)&Ab[(wr * 64 + i * 16 + l16) * 32 + ((l4 ^ ksw) * 8)];
        #pragma unroll
        for (int j = 0; j < 4; ++j)
            b[j] = *(const short8*)&Bb[(wc * 64 + j * 16 + l16) * 32 + ((l4 ^ ksw) * 8)];
        #pragma unroll
        for (int i = 0; i < 4; ++i)
            #pragma unroll
            for (int j = 0; j < 4; ++j)
                acc[i][j] = MFMA16(a[i], b[j], acc[i][j]);
        asm volatile("s_waitcnt vmcnt(0)" ::: "memory");
        __syncthreads();
    }

    #pragma unroll
    for (int j = 0; j < 4; ++j) {
        int n = (int)n0 + wc * 64 + j * 16 + l16;
        float bias = bp[n];
        #pragma unroll
        for (int i = 0; i < 4; ++i)
            #pragma unroll
            for (int r = 0; r < 4; ++r) {
                int m = (int)m0 + wr * 64 + i * 16 + l4 * 4 + r;
                out[(size_t)m * D_ + n] = acc[i][j][r] + bias;
            }
    }
}

// ---------------------------------------------------------------------------
extern "C" void kernel_launch(void* const* d_in, const int* in_sizes, int n_in,
                              void* d_out, int out_size, void* d_ws, size_t ws_size,
                              hipStream_t stream) {
    const float* x  = (const float*)d_in[0];
    const float* Wq = (const float*)d_in[1];
    const float* Wk = (const float*)d_in[2];
    const float* Wv = (const float*)d_in[3];
    const float* Wp = (const float*)d_in[4];
    const float* bp = (const float*)d_in[5];
    float* out = (float*)d_out;

    char* w = (char*)d_ws;
    unsigned short* xb  = (unsigned short*)w; w += (size_t)M_ * D_ * 2;
    unsigned short* Wt  = (unsigned short*)w; w += (size_t)3 * D_ * D_ * 2;
    unsigned short* Wpt = (unsigned short*)w; w += (size_t)D_ * D_ * 2;
    unsigned short* qb  = (unsigned short*)w; w += (size_t)BH_ * T_ * HD_ * 2;
    unsigned short* kb  = (unsigned short*)w; w += (size_t)BH_ * T_ * HD_ * 2;
    unsigned short* vT  = (unsigned short*)w; w += (size_t)BH_ * T_ * HD_ * 2;
    unsigned short* Ob  = (unsigned short*)w; w += (size_t)M_ * D_ * 2;

    cvt_x<<<dim3((M_ * D_ / 4 + 255) / 256), 256, 0, stream>>>(x, xb, M_ * D_ / 4);
    tcvt_qkv<<<dim3(16, 1, 48), 256, 0, stream>>>(Wq, Wk, Wv, Wt);
    tcvt<<<dim3(16, 16, 1), 256, 0, stream>>>(Wp, Wpt, D_, 0, 0, D_);

    qkv_mfma<<<dim3(1536), 256, 0, stream>>>(xb, Wt, qb, kb, vT);
    attn2<<<dim3(1024), 256, 0, stream>>>(qb, kb, vT, Ob);
    proj_mfma<<<dim3(512), 256, 0, stream>>>(Ob, Wpt, bp, out);
}

// Round 7
// 178.539 us; speedup vs baseline: 12.0383x; 1.1443x over previous
//
#include <hip/hip_runtime.h>
#include <hip/hip_bf16.h>

#define B_  4
#define T_  2048
#define D_  1024
#define H_  16
#define HD_ 64
#define M_  (B_ * T_)          // 8192 rows
#define BH_ (B_ * H_)          // 64

typedef __attribute__((ext_vector_type(8)))  short    short8;   // 8 x bf16 (4 VGPR)
typedef __attribute__((ext_vector_type(4)))  float    f32x4;
typedef __attribute__((ext_vector_type(16))) float    f32x16;
typedef __attribute__((ext_vector_type(4)))  unsigned short us4v;

#define MFMA16(a, b, c) __builtin_amdgcn_mfma_f32_16x16x32_bf16((a), (b), (c), 0, 0, 0)
#define MFMA32(a, b, c) __builtin_amdgcn_mfma_f32_32x32x16_bf16((a), (b), (c), 0, 0, 0)

__device__ __forceinline__ unsigned short f2bf(float f) {
    union { float f; unsigned u; } v; v.f = f;
    unsigned r = v.u + 0x7fffu + ((v.u >> 16) & 1u);   // round-nearest-even
    return (unsigned short)(r >> 16);
}

__device__ __forceinline__ float exp2_fast(float x) {
    float r; asm("v_exp_f32 %0, %1" : "=v"(r) : "v"(x)); return r;
}
__device__ __forceinline__ unsigned cvt_pk_bf16(float lo, float hi) {
    unsigned r; asm("v_cvt_pk_bf16_f32 %0, %1, %2" : "=v"(r) : "v"(lo), "v"(hi)); return r;
}

__device__ __forceinline__ void gl_lds16(const void* g, void* l) {
    __builtin_amdgcn_global_load_lds(
        (const __attribute__((address_space(1))) void*)g,
        (__attribute__((address_space(3))) void*)l, 16, 0, 0);
}

// ---------------------------------------------------------------------------
__global__ __launch_bounds__(256) void cvt_x(const float* __restrict__ x,
                                             unsigned short* __restrict__ xb, int n4) {
    int i = blockIdx.x * 256 + threadIdx.x;
    if (i < n4) {
        float4 v = ((const float4*)x)[i];
        us4v o;
        o[0] = f2bf(v.x); o[1] = f2bf(v.y); o[2] = f2bf(v.z); o[3] = f2bf(v.w);
        ((us4v*)xb)[i] = o;
    }
}

// ---------------------------------------------------------------------------
__global__ __launch_bounds__(256) void tcvt_qkv(
        const float* __restrict__ Wq, const float* __restrict__ Wk,
        const float* __restrict__ Wv, unsigned short* __restrict__ dst) {
    __shared__ float tile[64][65];
    int z = blockIdx.z;
    int sel = z >> 4, head = z & 15;
    const float* s = (sel == 0 ? Wq : (sel == 1 ? Wk : Wv)) + (size_t)head * D_ * HD_;
    int r0 = blockIdx.x * 64;               // k-range
    int tid = threadIdx.x;
    #pragma unroll
    for (int i = 0; i < 4; ++i) {
        int idx4 = i * 256 + tid;
        int r = idx4 >> 4, c4 = (idx4 & 15) * 4;
        float4 v = *(const float4*)&s[(size_t)(r0 + r) * HD_ + c4];
        tile[r][c4 + 0] = v.x; tile[r][c4 + 1] = v.y;
        tile[r][c4 + 2] = v.z; tile[r][c4 + 3] = v.w;
    }
    __syncthreads();
    #pragma unroll
    for (int i = 0; i < 4; ++i) {
        int idx4 = i * 256 + tid;
        int c = idx4 >> 4, r4 = (idx4 & 15) * 4;
        us4v o;
        o[0] = f2bf(tile[r4 + 0][c]); o[1] = f2bf(tile[r4 + 1][c]);
        o[2] = f2bf(tile[r4 + 2][c]); o[3] = f2bf(tile[r4 + 3][c]);
        *(us4v*)&dst[(size_t)(sel * 1024 + head * 64 + c) * D_ + r0 + r4] = o;
    }
}

// ---------------------------------------------------------------------------
__global__ __launch_bounds__(256) void tcvt(const float* __restrict__ src,
                                            unsigned short* __restrict__ dst,
                                            int src_ld, long src_z_str,
                                            int dst_row_base, int dst_ld) {
    __shared__ float tile[64][65];
    const float* s = src + (size_t)blockIdx.z * src_z_str;
    int r0 = blockIdx.x * 64, c0 = blockIdx.y * 64;
    int tid = threadIdx.x;
    #pragma unroll
    for (int i = 0; i < 4; ++i) {
        int idx4 = i * 256 + tid;
        int r = idx4 >> 4, c4 = (idx4 & 15) * 4;
        float4 v = *(const float4*)&s[(size_t)(r0 + r) * src_ld + c0 + c4];
        tile[r][c4 + 0] = v.x; tile[r][c4 + 1] = v.y;
        tile[r][c4 + 2] = v.z; tile[r][c4 + 3] = v.w;
    }
    __syncthreads();
    #pragma unroll
    for (int i = 0; i < 4; ++i) {
        int idx4 = i * 256 + tid;
        int c = idx4 >> 4, r4 = (idx4 & 15) * 4;
        us4v o;
        o[0] = f2bf(tile[r4 + 0][c]); o[1] = f2bf(tile[r4 + 1][c]);
        o[2] = f2bf(tile[r4 + 2][c]); o[3] = f2bf(tile[r4 + 3][c]);
        *(us4v*)&dst[(size_t)(dst_row_base + blockIdx.z * 64 + c0 + c) * dst_ld + r0 + r4] = o;
    }
}

// ---------------------------------------------------------------------------
// 2-phase double-buffered staging for the 128x128 GEMMs (unchanged).
// ---------------------------------------------------------------------------
__device__ __forceinline__ void stage_ab(const unsigned short* __restrict__ A,
                                         const unsigned short* __restrict__ Bt,
                                         size_t m0, size_t n0, int k0,
                                         unsigned short* Asb, unsigned short* Bsb,
                                         int tid) {
    #pragma unroll
    for (int c = 0; c < 2; ++c) {
        int idx = c * 256 + tid;            // 0..511 = (row 0..127) x (chunk 0..3)
        int row = idx >> 2, qp = idx & 3;
        int ql = qp ^ ((row >> 1) & 3);     // pre-swizzled source chunk
        gl_lds16(A  + (m0 + row) * (size_t)D_ + k0 + ql * 8, Asb + idx * 8);
        gl_lds16(Bt + (n0 + row) * (size_t)D_ + k0 + ql * 8, Bsb + idx * 8);
    }
}

// ---------------------------------------------------------------------------
// QKV GEMM v2 (unchanged from round 5)
// ---------------------------------------------------------------------------
__global__ __launch_bounds__(256) void qkv_mfma(
        const unsigned short* __restrict__ A,
        const unsigned short* __restrict__ Bt,
        unsigned short* __restrict__ qb, unsigned short* __restrict__ kb,
        unsigned short* __restrict__ vT) {
    __shared__ unsigned short As[2][128 * 32];
    __shared__ unsigned short Bs[2][128 * 32];
    const int tid = threadIdx.x;
    const int lane = tid & 63, wid = tid >> 6;
    const int l16 = lane & 15, l4 = lane >> 4;
    const int wr = wid >> 1, wc = wid & 1;
    const int ksw = (l16 >> 1) & 3;         // read-side swizzle

    const int orig = blockIdx.x;            // 1536 blocks, 1536%8==0 -> bijective
    const int wgid = (orig & 7) * 192 + (orig >> 3);
    const size_t m0 = (size_t)(wgid / 24) * 128;
    const size_t n0 = (size_t)(wgid % 24) * 128;

    f32x4 acc[4][4] = {};
    stage_ab(A, Bt, m0, n0, 0, As[0], Bs[0], tid);
    asm volatile("s_waitcnt vmcnt(0)" ::: "memory");
    __syncthreads();

    for (int t = 0; t < 32; ++t) {
        const int cur = t & 1;
        if (t < 31)
            stage_ab(A, Bt, m0, n0, (t + 1) * 32, As[cur ^ 1], Bs[cur ^ 1], tid);
        const unsigned short* Ab = As[cur];
        const unsigned short* Bb = Bs[cur];
        short8 a[4], b[4];
        #pragma unroll
        for (int i = 0; i < 4; ++i)
            a[i] = *(const short8*)&Ab[(wr * 64 + i * 16 + l16) * 32 + ((l4 ^ ksw) * 8)];
        #pragma unroll
        for (int j = 0; j < 4; ++j)
            b[j] = *(const short8*)&Bb[(wc * 64 + j * 16 + l16) * 32 + ((l4 ^ ksw) * 8)];
        #pragma unroll
        for (int i = 0; i < 4; ++i)
            #pragma unroll
            for (int j = 0; j < 4; ++j)
                acc[i][j] = MFMA16(a[i], b[j], acc[i][j]);
        asm volatile("s_waitcnt vmcnt(0)" ::: "memory");
        __syncthreads();
    }

    #pragma unroll
    for (int j = 0; j < 4; ++j) {
        int n = (int)n0 + wc * 64 + j * 16 + l16;
        int sel = n >> 10, h = (n >> 6) & (H_ - 1), e = n & 63;
        if (sel == 2) {
            #pragma unroll
            for (int i = 0; i < 4; ++i) {
                int m = (int)m0 + wr * 64 + i * 16 + l4 * 4;
                int b_ = m >> 11, tt = m & (T_ - 1);
                us4v o;
                #pragma unroll
                for (int r = 0; r < 4; ++r) o[r] = f2bf(acc[i][j][r]);
                *(us4v*)&vT[((size_t)(b_ * H_ + h) * HD_ + e) * T_ + tt] = o;
            }
        } else {
            float scale = (sel == 0) ? 0.18033688011112042f : 1.0f;  // 0.125*log2e
            unsigned short* dst = (sel == 0) ? qb : kb;
            #pragma unroll
            for (int i = 0; i < 4; ++i) {
                #pragma unroll
                for (int r = 0; r < 4; ++r) {
                    int m = (int)m0 + wr * 64 + i * 16 + l4 * 4 + r;
                    int b_ = m >> 11, tt = m & (T_ - 1);
                    dst[((size_t)(b_ * H_ + h) * T_ + tt) * HD_ + e] = f2bf(acc[i][j][r] * scale);
                }
            }
        }
    }
}

// ---------------------------------------------------------------------------
// Attention v6: 32x32x16 MFMA, swapped QK^T (S^T[key][query]); per-lane row
// softmax with FIXED shift (no online max: p = exp2(s-16), shift-invariant);
// P->A-frag relayout fully in-register via v_cvt_pk_bf16_f32 +
// v_permlane32_swap_b32; row-sum l accumulated by ones-row MFMA (zero VALU).
// Block: 4 waves x 32 queries x dual chain (q-tiles iA, 15-iA of 128 rows).
// ---------------------------------------------------------------------------
__device__ __forceinline__ void stage_kv(const unsigned short* kbase,
                                         const unsigned short* vbase,
                                         unsigned short* KsBuf, unsigned short* VsBuf,
                                         int jt, int wid, int lane) {
    int s = lane & 7, rl = lane >> 3;          // slot 0..7, row-in-chunk 0..7
    int cchunk = s ^ rl;                       // pre-swizzled source col-chunk
    #pragma unroll
    for (int cc = 0; cc < 2; ++cc) {
        int chunk = cc * 4 + wid;
        int r = chunk * 8 + rl;                // tile row 0..63
        gl_lds16(kbase + (size_t)(jt + r) * HD_ + cchunk * 8,
                 KsBuf + chunk * 512 + lane * 8);
        gl_lds16(vbase + (size_t)r * T_ + jt + cchunk * 8,
                 VsBuf + chunk * 512 + lane * 8);
    }
}

__device__ __forceinline__ void chain_step32(
        const unsigned short* __restrict__ Ksb,
        const unsigned short* __restrict__ Vsb,
        const short8 (&qf)[4], const short8 ones,
        int qrel, int partial, int l31, int hi, int l7,
        f32x16& o0, f32x16& o1, f32x16& lacc) {
    // ---- S^T = K Q^T : 2 key-halves x 4 k-chunks ----
    f32x16 s0 = {}, s1 = {};
    __builtin_amdgcn_s_setprio(1);
    #pragma unroll
    for (int c = 0; c < 4; ++c) {
        int sl = (((2 * c + hi) ^ l7) * 8);
        short8 k0 = *(const short8*)&Ksb[l31 * 64 + sl];
        short8 k1 = *(const short8*)&Ksb[(32 + l31) * 64 + sl];
        s0 = MFMA32(k0, qf[c], s0);
        s1 = MFMA32(k1, qf[c], s1);
    }
    __builtin_amdgcn_s_setprio(0);

    // ---- causal mask (diagonal steps only; wave-uniform branch) ----
    if (partial) {
        #pragma unroll
        for (int r = 0; r < 16; ++r) {
            int kl = (r & 3) + 8 * (r >> 2) + 4 * hi;
            s0[r] = (kl > qrel) ? -1e30f : s0[r];
            s1[r] = (kl + 32 > qrel) ? -1e30f : s1[r];
        }
    }

    // ---- p = exp2(s - 16) -> bf16 words -> permlane swap -> B-fragments ----
    unsigned w[4][4];
    #pragma unroll
    for (int kh = 0; kh < 2; ++kh) {
        float p[16];
        #pragma unroll
        for (int r = 0; r < 16; ++r) {
            float v = (kh == 0) ? s0[r] : s1[r];
            p[r] = exp2_fast(v - 16.0f);
        }
        unsigned c0 = cvt_pk_bf16(p[0], p[1]),   c1 = cvt_pk_bf16(p[2], p[3]);
        unsigned d0 = cvt_pk_bf16(p[4], p[5]),   d1 = cvt_pk_bf16(p[6], p[7]);
        unsigned e0 = cvt_pk_bf16(p[8], p[9]),   e1 = cvt_pk_bf16(p[10], p[11]);
        unsigned f0 = cvt_pk_bf16(p[12], p[13]), f1 = cvt_pk_bf16(p[14], p[15]);
        asm("v_permlane32_swap_b32 %0, %1" : "+v"(c0), "+v"(d0));
        asm("v_permlane32_swap_b32 %0, %1" : "+v"(c1), "+v"(d1));
        asm("v_permlane32_swap_b32 %0, %1" : "+v"(e0), "+v"(f0));
        asm("v_permlane32_swap_b32 %0, %1" : "+v"(e1), "+v"(f1));
        w[2 * kh][0] = c0;     w[2 * kh][1] = c1;
        w[2 * kh][2] = d0;     w[2 * kh][3] = d1;
        w[2 * kh + 1][0] = e0; w[2 * kh + 1][1] = e1;
        w[2 * kh + 1][2] = f0; w[2 * kh + 1][3] = f1;
    }

    // ---- O^T += V^T P ; l-row via ones MFMA ----
    #pragma unroll
    for (int kc = 0; kc < 4; ++kc) {
        union { unsigned u[4]; short8 s8; } pu;
        pu.u[0] = w[kc][0]; pu.u[1] = w[kc][1];
        pu.u[2] = w[kc][2]; pu.u[3] = w[kc][3];
        int sl = (((2 * kc + hi) ^ l7) * 8);
        short8 v0 = *(const short8*)&Vsb[l31 * 64 + sl];
        short8 v1 = *(const short8*)&Vsb[(32 + l31) * 64 + sl];
        __builtin_amdgcn_s_setprio(1);
        o0 = MFMA32(v0, pu.s8, o0);
        o1 = MFMA32(v1, pu.s8, o1);
        lacc = MFMA32(ones, pu.s8, lacc);
        __builtin_amdgcn_s_setprio(0);
    }
}

__global__ __launch_bounds__(256, 2) void attn3(
        const unsigned short* __restrict__ qb, const unsigned short* __restrict__ kb,
        const unsigned short* __restrict__ vT, unsigned short* __restrict__ Ob) {
    __shared__ unsigned short Ks[2][64 * 64];
    __shared__ unsigned short Vs[2][64 * 64];

    const int blk = blockIdx.x;                        // 0..511
    const int bh = (blk & 7) + 8 * ((blk >> 3) & 7);   // XCD-local bh
    const int pair = blk >> 6;                         // 0..7
    const int iA = pair, iB = 15 - pair;               // 128-row q-tiles
    const int b = bh >> 4, h = bh & (H_ - 1);

    const int lane = threadIdx.x & 63, wid = threadIdx.x >> 6;
    const int l31 = lane & 31, hi = lane >> 5, l7 = lane & 7;
    const int qloA = iA * 128 + wid * 32;
    const int qloB = iB * 128 + wid * 32;

    const unsigned short* kbase = kb + (size_t)bh * T_ * HD_;
    const unsigned short* vbase = vT + (size_t)bh * HD_ * T_;
    const unsigned short* qbase = qb + (size_t)bh * T_ * HD_;

    short8 qfA[4], qfB[4];
    {
        const unsigned short* qr = qbase + (size_t)(qloA + l31) * HD_;
        #pragma unroll
        for (int c = 0; c < 4; ++c)
            qfA[c] = *(const short8*)(qr + 16 * c + 8 * hi);
        qr = qbase + (size_t)(qloB + l31) * HD_;
        #pragma unroll
        for (int c = 0; c < 4; ++c)
            qfB[c] = *(const short8*)(qr + 16 * c + 8 * hi);
    }
    short8 ones;
    #pragma unroll
    for (int i = 0; i < 8; ++i) ones[i] = (short)0x3F80;   // 1.0 bf16

    f32x16 oA0 = {}, oA1 = {}, oB0 = {}, oB1 = {}, laA = {}, laB = {};

    stage_kv(kbase, vbase, Ks[0], Vs[0], 0, wid, lane);
    asm volatile("s_waitcnt vmcnt(0)" ::: "memory");
    __syncthreads();

    const int jmax = 2 * iB + 1;
    for (int j = 0; j <= jmax; ++j) {
        const int cur = j & 1;
        if (j < jmax)
            stage_kv(kbase, vbase, Ks[cur ^ 1], Vs[cur ^ 1], (j + 1) * 64, wid, lane);
        const unsigned short* Ksb = Ks[cur];
        const unsigned short* Vsb = Vs[cur];
        const int kb0 = 64 * j;
        if (kb0 <= qloA + 31)
            chain_step32(Ksb, Vsb, qfA, ones, qloA + l31 - kb0,
                         (kb0 + 63 > qloA) ? 1 : 0, l31, hi, l7, oA0, oA1, laA);
        if (kb0 <= qloB + 31)
            chain_step32(Ksb, Vsb, qfB, ones, qloB + l31 - kb0,
                         (kb0 + 63 > qloB) ? 1 : 0, l31, hi, l7, oB0, oB1, laB);
        asm volatile("s_waitcnt vmcnt(0)" ::: "memory");
        __syncthreads();
    }

    // ---- epilogue: e = (r&3) + 8*(r>>2) + 4*hi + 32*eh,  q = l31 ----
    {
        float inv = 1.0f / laA[0];
        unsigned short* ob = Ob + ((size_t)(b * T_ + qloA + l31)) * D_ + h * HD_;
        #pragma unroll
        for (int eh = 0; eh < 2; ++eh) {
            const f32x16& o = eh ? oA1 : oA0;
            #pragma unroll
            for (int g = 0; g < 4; ++g) {
                uint2 wv;
                wv.x = cvt_pk_bf16(o[4 * g] * inv, o[4 * g + 1] * inv);
                wv.y = cvt_pk_bf16(o[4 * g + 2] * inv, o[4 * g + 3] * inv);
                *(uint2*)&ob[8 * g + 4 * hi + 32 * eh] = wv;
            }
        }
    }
    {
        float inv = 1.0f / laB[0];
        unsigned short* ob = Ob + ((size_t)(b * T_ + qloB + l31)) * D_ + h * HD_;
        #pragma unroll
        for (int eh = 0; eh < 2; ++eh) {
            const f32x16& o = eh ? oB1 : oB0;
            #pragma unroll
            for (int g = 0; g < 4; ++g) {
                uint2 wv;
                wv.x = cvt_pk_bf16(o[4 * g] * inv, o[4 * g + 1] * inv);
                wv.y = cvt_pk_bf16(o[4 * g + 2] * inv, o[4 * g + 3] * inv);
                *(uint2*)&ob[8 * g + 4 * hi + 32 * eh] = wv;
            }
        }
    }
}

// ---------------------------------------------------------------------------
// Output projection v2 (unchanged from round 5)
// ---------------------------------------------------------------------------
__global__ __launch_bounds__(256) void proj_mfma(
        const unsigned short* __restrict__ A,
        const unsigned short* __restrict__ Bt,
        const float* __restrict__ bp, float* __restrict__ out) {
    __shared__ unsigned short As[2][128 * 32];
    __shared__ unsigned short Bs[2][128 * 32];
    const int tid = threadIdx.x;
    const int lane = tid & 63, wid = tid >> 6;
    const int l16 = lane & 15, l4 = lane >> 4;
    const int wr = wid >> 1, wc = wid & 1;
    const int ksw = (l16 >> 1) & 3;

    const int orig = blockIdx.x;            // 512 blocks, 512%8==0 -> bijective
    const int wgid = (orig & 7) * 64 + (orig >> 3);
    const size_t m0 = (size_t)(wgid >> 3) * 128;
    const size_t n0 = (size_t)(wgid & 7) * 128;

    f32x4 acc[4][4] = {};
    stage_ab(A, Bt, m0, n0, 0, As[0], Bs[0], tid);
    asm volatile("s_waitcnt vmcnt(0)" ::: "memory");
    __syncthreads();

    for (int t = 0; t < 32; ++t) {
        const int cur = t & 1;
        if (t < 31)
            stage_ab(A, Bt, m0, n0, (t + 1) * 32, As[cur ^ 1], Bs[cur ^ 1], tid);
        const unsigned short* Ab = As[cur];
        const unsigned short* Bb = Bs[cur];
        short8 a[4], b[4];
        #pragma unroll
        for (int i = 0; i < 4; ++i)
            a[i] = *(const short8*)&Ab[(wr * 64 + i * 16 + l16) * 32 + ((l4 ^ ksw) * 8)];
        #pragma unroll
        for (int j = 0; j < 4; ++j)
            b[j] = *(const short8*)&Bb[(wc * 64 + j * 16 + l16) * 32 + ((l4 ^ ksw) * 8)];
        #pragma unroll
        for (int i = 0; i < 4; ++i)
            #pragma unroll
            for (int j = 0; j < 4; ++j)
                acc[i][j] = MFMA16(a[i], b[j], acc[i][j]);
        asm volatile("s_waitcnt vmcnt(0)" ::: "memory");
        __syncthreads();
    }

    #pragma unroll
    for (int j = 0; j < 4; ++j) {
        int n = (int)n0 + wc * 64 + j * 16 + l16;
        float bias = bp[n];
        #pragma unroll
        for (int i = 0; i < 4; ++i)
            #pragma unroll
            for (int r = 0; r < 4; ++r) {
                int m = (int)m0 + wr * 64 + i * 16 + l4 * 4 + r;
                out[(size_t)m * D_ + n] = acc[i][j][r] + bias;
            }
    }
}

// ---------------------------------------------------------------------------
extern "C" void kernel_launch(void* const* d_in, const int* in_sizes, int n_in,
                              void* d_out, int out_size, void* d_ws, size_t ws_size,
                              hipStream_t stream) {
    const float* x  = (const float*)d_in[0];
    const float* Wq = (const float*)d_in[1];
    const float* Wk = (const float*)d_in[2];
    const float* Wv = (const float*)d_in[3];
    const float* Wp = (const float*)d_in[4];
    const float* bp = (const float*)d_in[5];
    float* out = (float*)d_out;

    char* w = (char*)d_ws;
    unsigned short* xb  = (unsigned short*)w; w += (size_t)M_ * D_ * 2;
    unsigned short* Wt  = (unsigned short*)w; w += (size_t)3 * D_ * D_ * 2;
    unsigned short* Wpt = (unsigned short*)w; w += (size_t)D_ * D_ * 2;
    unsigned short* qb  = (unsigned short*)w; w += (size_t)BH_ * T_ * HD_ * 2;
    unsigned short* kb  = (unsigned short*)w; w += (size_t)BH_ * T_ * HD_ * 2;
    unsigned short* vT  = (unsigned short*)w; w += (size_t)BH_ * T_ * HD_ * 2;
    unsigned short* Ob  = (unsigned short*)w; w += (size_t)M_ * D_ * 2;

    cvt_x<<<dim3((M_ * D_ / 4 + 255) / 256), 256, 0, stream>>>(x, xb, M_ * D_ / 4);
    tcvt_qkv<<<dim3(16, 1, 48), 256, 0, stream>>>(Wq, Wk, Wv, Wt);
    tcvt<<<dim3(16, 16, 1), 256, 0, stream>>>(Wp, Wpt, D_, 0, 0, D_);

    qkv_mfma<<<dim3(1536), 256, 0, stream>>>(xb, Wt, qb, kb, vT);
    attn3<<<dim3(512), 256, 0, stream>>>(qb, kb, vT, Ob);
    proj_mfma<<<dim3(512), 256, 0, stream>>>(Ob, Wpt, bp, out);
}